// Round 21
// baseline (3439.432 us; speedup 1.0000x reference)
//
#include <hip/hip_runtime.h>
#include <cstdint>

typedef unsigned short u16;
typedef __attribute__((ext_vector_type(4))) float f32x4;
typedef __attribute__((ext_vector_type(8))) __bf16 bf16x8;

#define DEV static __device__ __forceinline__

DEV u16 f2b(float f){
    unsigned int u = __builtin_bit_cast(unsigned int, f);
    u += 0x7fffu + ((u >> 16) & 1u);
    return (u16)(u >> 16);
}
DEV float b2f(u16 u){ return __builtin_bit_cast(float, (unsigned int)u << 16); }
DEV float gelu_f(float x){
    float x3 = x*x*x;
    return 0.5f*x*(1.f + tanhf(0.7978845608f*(x + 0.044715f*x3)));
}

DEV void gload16(const u16* g, u16* l){
    __builtin_amdgcn_global_load_lds(
        (const __attribute__((address_space(1))) unsigned int*)g,
        (__attribute__((address_space(3))) unsigned int*)l,
        16, 0, 0);
}

// ---------------- MFMA GEMM plain (verified) ----------------
template<int MODE>
__global__ __launch_bounds__(256) void mgemm(
    const u16* __restrict__ A, const u16* __restrict__ Bt,
    float* __restrict__ Cf, u16* __restrict__ Cb,
    const float* __restrict__ bias, const float* __restrict__ rowscale,
    int M, int N, int K, int ldc){
    int nb = blockIdx.x, mb = blockIdx.y;
    int tid = threadIdx.x, lane = tid & 63, w = tid >> 6;
    int rr = lane & 15, hi = lane >> 4;
    int wm = (w >> 1)*64, wn = (w & 1)*64;
    __shared__ u16 As[128*64];
    __shared__ u16 Bs[128*64];
    int sw_r = (rr & 7) * 8;
    int ce = (((lane&7) ^ (lane>>3)))*8;
    const u16* ap[4]; const u16* bp[4];
    u16* adst[4]; u16* bdst[4];
    #pragma unroll
    for (int p=0;p<4;++p){
        int r = (w*4+p)*8 + (lane>>3);
        ap[p] = A  + (size_t)(mb*128 + r)*K + ce;
        bp[p] = Bt + (size_t)(nb*128 + r)*K + ce;
        adst[p] = &As[(w*4+p)*512];
        bdst[p] = &Bs[(w*4+p)*512];
    }
    f32x4 acc[4][4];
    #pragma unroll
    for (int mt=0;mt<4;++mt)
        #pragma unroll
        for (int nt=0;nt<4;++nt) acc[mt][nt] = (f32x4){0.f,0.f,0.f,0.f};

    for (int k0=0; k0<K; k0+=64){
        #pragma unroll
        for (int p=0;p<4;++p){
            gload16(ap[p] + k0, adst[p]);
            gload16(bp[p] + k0, bdst[p]);
        }
        __syncthreads();
        #pragma unroll
        for (int kc=0;kc<2;++kc){
            int kk = (kc*32 + hi*8) ^ sw_r;
            bf16x8 af[4], bfv[4];
            #pragma unroll
            for (int mt=0;mt<4;++mt) af[mt]  = *(const bf16x8*)&As[(wm+mt*16+rr)*64 + kk];
            #pragma unroll
            for (int nt=0;nt<4;++nt) bfv[nt] = *(const bf16x8*)&Bs[(wn+nt*16+rr)*64 + kk];
            #pragma unroll
            for (int mt=0;mt<4;++mt)
                #pragma unroll
                for (int nt=0;nt<4;++nt)
                    acc[mt][nt] = __builtin_amdgcn_mfma_f32_16x16x32_bf16(af[mt], bfv[nt], acc[mt][nt], 0,0,0);
        }
        __syncthreads();
    }
    #pragma unroll
    for (int mt=0;mt<4;++mt){
        #pragma unroll
        for (int j=0;j<4;++j){
            int m = wm + mt*16 + hi*4 + j;
            size_t orow = (size_t)(mb*128 + m);
            #pragma unroll
            for (int nt=0;nt<4;++nt){
                int col = nb*128 + wn + nt*16 + rr;
                float v = acc[mt][nt][j];
                if (MODE == 0)      Cf[orow*ldc + col] = v;
                else if (MODE == 1) Cf[orow*ldc + col] += v;
            }
        }
    }
}

// ---------------- FUSED split-bf16 GEMM (dense, verified) ----------------
template<int MODE>
__global__ __launch_bounds__(256) void mgemm_s(
    const u16* __restrict__ Ah, const u16* __restrict__ Al,
    const u16* __restrict__ Bth, const u16* __restrict__ Btl,
    float* __restrict__ Cf, int M, int N, int K, int ldc){
    int nb = blockIdx.x, mb = blockIdx.y;
    int tid = threadIdx.x, lane = tid & 63, w = tid >> 6;
    int rr = lane & 15, hi = lane >> 4;
    int wm = (w >> 1)*64, wn = (w & 1)*64;
    __shared__ u16 Ash[128*64];
    __shared__ u16 Asl[128*64];
    __shared__ u16 Bsh[128*64];
    __shared__ u16 Bsl[128*64];
    int sw_r = (rr & 7) * 8;
    int ce = (((lane&7) ^ (lane>>3)))*8;
    const u16* ahp[4]; const u16* alp[4]; const u16* bhp[4]; const u16* blp[4];
    u16 *ahd[4], *ald[4], *bhd[4], *bld[4];
    #pragma unroll
    for (int p=0;p<4;++p){
        int r = (w*4+p)*8 + (lane>>3);
        size_t ao = (size_t)(mb*128 + r)*K + ce;
        size_t bo = (size_t)(nb*128 + r)*K + ce;
        ahp[p] = Ah + ao;  alp[p] = Al + ao;
        bhp[p] = Bth + bo; blp[p] = Btl + bo;
        ahd[p] = &Ash[(w*4+p)*512]; ald[p] = &Asl[(w*4+p)*512];
        bhd[p] = &Bsh[(w*4+p)*512]; bld[p] = &Bsl[(w*4+p)*512];
    }
    f32x4 acc[4][4];
    #pragma unroll
    for (int mt=0;mt<4;++mt)
        #pragma unroll
        for (int nt=0;nt<4;++nt) acc[mt][nt] = (f32x4){0.f,0.f,0.f,0.f};

    for (int k0=0; k0<K; k0+=64){
        #pragma unroll
        for (int p=0;p<4;++p){
            gload16(ahp[p] + k0, ahd[p]);
            gload16(alp[p] + k0, ald[p]);
            gload16(bhp[p] + k0, bhd[p]);
            gload16(blp[p] + k0, bld[p]);
        }
        __syncthreads();
        #pragma unroll
        for (int kc=0;kc<2;++kc){
            int kk = (kc*32 + hi*8) ^ sw_r;
            bf16x8 afh[4], afl[4], bfh[4], bfl[4];
            #pragma unroll
            for (int mt=0;mt<4;++mt){
                afh[mt] = *(const bf16x8*)&Ash[(wm+mt*16+rr)*64 + kk];
                afl[mt] = *(const bf16x8*)&Asl[(wm+mt*16+rr)*64 + kk];
            }
            #pragma unroll
            for (int nt=0;nt<4;++nt){
                bfh[nt] = *(const bf16x8*)&Bsh[(wn+nt*16+rr)*64 + kk];
                bfl[nt] = *(const bf16x8*)&Bsl[(wn+nt*16+rr)*64 + kk];
            }
            #pragma unroll
            for (int mt=0;mt<4;++mt)
                #pragma unroll
                for (int nt=0;nt<4;++nt){
                    acc[mt][nt] = __builtin_amdgcn_mfma_f32_16x16x32_bf16(afh[mt], bfh[nt], acc[mt][nt], 0,0,0);
                    acc[mt][nt] = __builtin_amdgcn_mfma_f32_16x16x32_bf16(afh[mt], bfl[nt], acc[mt][nt], 0,0,0);
                    acc[mt][nt] = __builtin_amdgcn_mfma_f32_16x16x32_bf16(afl[mt], bfh[nt], acc[mt][nt], 0,0,0);
                }
        }
        __syncthreads();
    }
    #pragma unroll
    for (int mt=0;mt<4;++mt){
        #pragma unroll
        for (int j=0;j<4;++j){
            int m = wm + mt*16 + hi*4 + j;
            size_t orow = (size_t)(mb*128 + m);
            #pragma unroll
            for (int nt=0;nt<4;++nt){
                int col = nb*128 + wn + nt*16 + rr;
                float v = acc[mt][nt][j];
                if (MODE == 0)      Cf[orow*ldc + col] = v;
                else if (MODE == 1) Cf[orow*ldc + col] += v;
            }
        }
    }
}

// ---------------- GROUPED split expert GEMM: mb = blockIdx.x (B-tile L2 reuse) ----------------
template<bool UP>
__global__ __launch_bounds__(256) void mgemm_gs(
    const u16* __restrict__ Ah, const u16* __restrict__ Al,
    const u16* __restrict__ Bth, const u16* __restrict__ Btl,
    float* __restrict__ Cf, u16* __restrict__ OutH, u16* __restrict__ OutL,
    const float* __restrict__ b1all,
    const int* __restrict__ tok, const int* __restrict__ counts, const int* __restrict__ offs,
    int N, int K){
    int e = blockIdx.z;
    int cnt = counts[e];
    int mb = blockIdx.x, nb = blockIdx.y;
    if (mb*128 >= cnt) return;
    int slot0 = offs[e];
    const u16* Bh = Bth + (size_t)e*N*K;
    const u16* Bl = Btl + (size_t)e*N*K;
    int tid = threadIdx.x, lane = tid & 63, w = tid >> 6;
    int rr = lane & 15, hi = lane >> 4;
    int wm = (w >> 1)*64, wn = (w & 1)*64;
    __shared__ u16 Ash[128*64];
    __shared__ u16 Asl[128*64];
    __shared__ u16 Bsh[128*64];
    __shared__ u16 Bsl[128*64];
    int sw_r = (rr & 7) * 8;
    int ce = (((lane&7) ^ (lane>>3)))*8;
    const u16* ahp[4]; const u16* alp[4]; const u16* bhp[4]; const u16* blp[4];
    u16 *ahd[4], *ald[4], *bhd[4], *bld[4];
    #pragma unroll
    for (int p=0;p<4;++p){
        int r = (w*4+p)*8 + (lane>>3);
        int lr = mb*128 + r;
        int lc = lr < cnt ? lr : (cnt-1);
        size_t arow = UP ? (size_t)tok[slot0 + lc] : (size_t)(slot0 + lc);
        ahp[p] = Ah + arow*K + ce;
        alp[p] = Al + arow*K + ce;
        bhp[p] = Bh + (size_t)(nb*128 + r)*K + ce;
        blp[p] = Bl + (size_t)(nb*128 + r)*K + ce;
        ahd[p] = &Ash[(w*4+p)*512]; ald[p] = &Asl[(w*4+p)*512];
        bhd[p] = &Bsh[(w*4+p)*512]; bld[p] = &Bsl[(w*4+p)*512];
    }
    f32x4 acc[4][4];
    #pragma unroll
    for (int mt=0;mt<4;++mt)
        #pragma unroll
        for (int nt=0;nt<4;++nt) acc[mt][nt] = (f32x4){0.f,0.f,0.f,0.f};

    for (int k0=0; k0<K; k0+=64){
        #pragma unroll
        for (int p=0;p<4;++p){
            gload16(ahp[p] + k0, ahd[p]);
            gload16(alp[p] + k0, ald[p]);
            gload16(bhp[p] + k0, bhd[p]);
            gload16(blp[p] + k0, bld[p]);
        }
        __syncthreads();
        #pragma unroll
        for (int kc=0;kc<2;++kc){
            int kk = (kc*32 + hi*8) ^ sw_r;
            bf16x8 afh[4], afl[4], bfh[4], bfl[4];
            #pragma unroll
            for (int mt=0;mt<4;++mt){
                afh[mt] = *(const bf16x8*)&Ash[(wm+mt*16+rr)*64 + kk];
                afl[mt] = *(const bf16x8*)&Asl[(wm+mt*16+rr)*64 + kk];
            }
            #pragma unroll
            for (int nt=0;nt<4;++nt){
                bfh[nt] = *(const bf16x8*)&Bsh[(wn+nt*16+rr)*64 + kk];
                bfl[nt] = *(const bf16x8*)&Bsl[(wn+nt*16+rr)*64 + kk];
            }
            #pragma unroll
            for (int mt=0;mt<4;++mt)
                #pragma unroll
                for (int nt=0;nt<4;++nt){
                    acc[mt][nt] = __builtin_amdgcn_mfma_f32_16x16x32_bf16(afh[mt], bfh[nt], acc[mt][nt], 0,0,0);
                    acc[mt][nt] = __builtin_amdgcn_mfma_f32_16x16x32_bf16(afh[mt], bfl[nt], acc[mt][nt], 0,0,0);
                    acc[mt][nt] = __builtin_amdgcn_mfma_f32_16x16x32_bf16(afl[mt], bfh[nt], acc[mt][nt], 0,0,0);
                }
        }
        __syncthreads();
    }
    const float* b1e = UP ? (b1all + (size_t)e*N) : nullptr;
    #pragma unroll
    for (int mt=0;mt<4;++mt){
        #pragma unroll
        for (int j=0;j<4;++j){
            int m = wm + mt*16 + hi*4 + j;
            int lr = mb*128 + m;
            if (lr >= cnt) continue;
            size_t orow = (size_t)(slot0 + lr);
            #pragma unroll
            for (int nt=0;nt<4;++nt){
                int col = nb*128 + wn + nt*16 + rr;
                float v = acc[mt][nt][j];
                if (UP){
                    float g = gelu_f(v + b1e[col]);
                    u16 h = f2b(g);
                    OutH[orow*N + col] = h;
                    OutL[orow*N + col] = f2b(g - b2f(h));
                } else {
                    Cf[orow*N + col] = v;
                }
            }
        }
    }
}

// ---------------- GROUPED plain expert GEMM (L1): mb = blockIdx.x ----------------
template<bool UP>
__global__ __launch_bounds__(256) void mgemm_gp(
    const u16* __restrict__ A, const u16* __restrict__ Bt,
    float* __restrict__ Cf, u16* __restrict__ Cb, const float* __restrict__ b1all,
    const int* __restrict__ tok, const int* __restrict__ counts, const int* __restrict__ offs,
    int N, int K){
    int e = blockIdx.z;
    int cnt = counts[e];
    int mb = blockIdx.x, nb = blockIdx.y;
    if (mb*128 >= cnt) return;
    int slot0 = offs[e];
    const u16* Bte = Bt + (size_t)e*N*K;
    int tid = threadIdx.x, lane = tid & 63, w = tid >> 6;
    int rr = lane & 15, hi = lane >> 4;
    int wm = (w >> 1)*64, wn = (w & 1)*64;
    __shared__ u16 As[128*64];
    __shared__ u16 Bs[128*64];
    int sw_r = (rr & 7) * 8;
    int ce = (((lane&7) ^ (lane>>3)))*8;
    const u16* aptr[4]; const u16* bptr[4];
    u16 *adst[4], *bdst[4];
    #pragma unroll
    for (int p=0;p<4;++p){
        int r = (w*4+p)*8 + (lane>>3);
        int lr = mb*128 + r;
        int lc = lr < cnt ? lr : (cnt-1);
        size_t arow = UP ? (size_t)tok[slot0 + lc] : (size_t)(slot0 + lc);
        aptr[p] = A  + arow*K + ce;
        bptr[p] = Bte + (size_t)(nb*128 + r)*K + ce;
        adst[p] = &As[(w*4+p)*512];
        bdst[p] = &Bs[(w*4+p)*512];
    }
    f32x4 acc[4][4];
    #pragma unroll
    for (int mt=0;mt<4;++mt)
        #pragma unroll
        for (int nt=0;nt<4;++nt) acc[mt][nt] = (f32x4){0.f,0.f,0.f,0.f};

    for (int k0=0; k0<K; k0+=64){
        #pragma unroll
        for (int p=0;p<4;++p){
            gload16(aptr[p] + k0, adst[p]);
            gload16(bptr[p] + k0, bdst[p]);
        }
        __syncthreads();
        #pragma unroll
        for (int kc=0;kc<2;++kc){
            int kk = (kc*32 + hi*8) ^ sw_r;
            bf16x8 af[4], bfv[4];
            #pragma unroll
            for (int mt=0;mt<4;++mt) af[mt]  = *(const bf16x8*)&As[(wm+mt*16+rr)*64 + kk];
            #pragma unroll
            for (int nt=0;nt<4;++nt) bfv[nt] = *(const bf16x8*)&Bs[(wn+nt*16+rr)*64 + kk];
            #pragma unroll
            for (int mt=0;mt<4;++mt)
                #pragma unroll
                for (int nt=0;nt<4;++nt)
                    acc[mt][nt] = __builtin_amdgcn_mfma_f32_16x16x32_bf16(af[mt], bfv[nt], acc[mt][nt], 0,0,0);
        }
        __syncthreads();
    }
    const float* b1e = UP ? (b1all + (size_t)e*N) : nullptr;
    #pragma unroll
    for (int mt=0;mt<4;++mt){
        #pragma unroll
        for (int j=0;j<4;++j){
            int m = wm + mt*16 + hi*4 + j;
            int lr = mb*128 + m;
            if (lr >= cnt) continue;
            size_t orow = (size_t)(slot0 + lr);
            #pragma unroll
            for (int nt=0;nt<4;++nt){
                int col = nb*128 + wn + nt*16 + rr;
                float v = acc[mt][nt][j];
                if (UP) Cb[orow*N + col] = f2b(gelu_f(v + b1e[col]));
                else    Cf[orow*N + col] = v;
            }
        }
    }
}

// ---------------- chunked expert GEMMs (fallback path, verified r19) ----------------
template<bool UP>
__global__ __launch_bounds__(256) void mgemm_xs(
    const u16* __restrict__ Ah, const u16* __restrict__ Al,
    const u16* __restrict__ Bth, const u16* __restrict__ Btl,
    float* __restrict__ Cf,
    const int* __restrict__ tok, const int* __restrict__ counts, const int* __restrict__ offs,
    int e, int chunk, int N, int K){
    int cnt = counts[e];
    int rem = cnt - chunk*2048;
    int nb = blockIdx.x, mb = blockIdx.y;
    if (mb*128 >= rem) return;
    int Mloc = rem < 2048 ? rem : 2048;
    int slot0 = offs[e] + chunk*2048;
    int tid = threadIdx.x, lane = tid & 63, w = tid >> 6;
    int rr = lane & 15, hi = lane >> 4;
    int wm = (w >> 1)*64, wn = (w & 1)*64;
    __shared__ u16 Ash[128*64];
    __shared__ u16 Asl[128*64];
    __shared__ u16 Bsh[128*64];
    __shared__ u16 Bsl[128*64];
    int sw_r = (rr & 7) * 8;
    int ce = (((lane&7) ^ (lane>>3)))*8;
    const u16* ahp[4]; const u16* alp[4]; const u16* bhp[4]; const u16* blp[4];
    u16 *ahd[4], *ald[4], *bhd[4], *bld[4];
    #pragma unroll
    for (int p=0;p<4;++p){
        int r = (w*4+p)*8 + (lane>>3);
        int lr = mb*128 + r;
        int lc = lr < Mloc ? lr : (Mloc-1);
        size_t arow = UP ? (size_t)tok[slot0 + lc] : (size_t)lc;
        ahp[p] = Ah + arow*K + ce;
        alp[p] = Al + arow*K + ce;
        bhp[p] = Bth + (size_t)(nb*128 + r)*K + ce;
        blp[p] = Btl + (size_t)(nb*128 + r)*K + ce;
        ahd[p] = &Ash[(w*4+p)*512]; ald[p] = &Asl[(w*4+p)*512];
        bhd[p] = &Bsh[(w*4+p)*512]; bld[p] = &Bsl[(w*4+p)*512];
    }
    f32x4 acc[4][4];
    #pragma unroll
    for (int mt=0;mt<4;++mt)
        #pragma unroll
        for (int nt=0;nt<4;++nt) acc[mt][nt] = (f32x4){0.f,0.f,0.f,0.f};

    for (int k0=0; k0<K; k0+=64){
        #pragma unroll
        for (int p=0;p<4;++p){
            gload16(ahp[p] + k0, ahd[p]);
            gload16(alp[p] + k0, ald[p]);
            gload16(bhp[p] + k0, bhd[p]);
            gload16(blp[p] + k0, bld[p]);
        }
        __syncthreads();
        #pragma unroll
        for (int kc=0;kc<2;++kc){
            int kk = (kc*32 + hi*8) ^ sw_r;
            bf16x8 afh[4], afl[4], bfh[4], bfl[4];
            #pragma unroll
            for (int mt=0;mt<4;++mt){
                afh[mt] = *(const bf16x8*)&Ash[(wm+mt*16+rr)*64 + kk];
                afl[mt] = *(const bf16x8*)&Asl[(wm+mt*16+rr)*64 + kk];
            }
            #pragma unroll
            for (int nt=0;nt<4;++nt){
                bfh[nt] = *(const bf16x8*)&Bsh[(wn+nt*16+rr)*64 + kk];
                bfl[nt] = *(const bf16x8*)&Bsl[(wn+nt*16+rr)*64 + kk];
            }
            #pragma unroll
            for (int mt=0;mt<4;++mt)
                #pragma unroll
                for (int nt=0;nt<4;++nt){
                    acc[mt][nt] = __builtin_amdgcn_mfma_f32_16x16x32_bf16(afh[mt], bfh[nt], acc[mt][nt], 0,0,0);
                    acc[mt][nt] = __builtin_amdgcn_mfma_f32_16x16x32_bf16(afh[mt], bfl[nt], acc[mt][nt], 0,0,0);
                    acc[mt][nt] = __builtin_amdgcn_mfma_f32_16x16x32_bf16(afl[mt], bfh[nt], acc[mt][nt], 0,0,0);
                }
        }
        __syncthreads();
    }
    #pragma unroll
    for (int mt=0;mt<4;++mt){
        #pragma unroll
        for (int j=0;j<4;++j){
            int m = wm + mt*16 + hi*4 + j;
            int lr = mb*128 + m;
            if (lr >= Mloc) continue;
            size_t orow = UP ? (size_t)lr : (size_t)(slot0 + lr);
            #pragma unroll
            for (int nt=0;nt<4;++nt){
                int col = nb*128 + wn + nt*16 + rr;
                Cf[orow*N + col] = acc[mt][nt][j];
            }
        }
    }
}

template<int MODE, bool UP>
__global__ __launch_bounds__(256) void mgemm_x(
    const u16* __restrict__ A, const u16* __restrict__ Bt,
    float* __restrict__ Cf, u16* __restrict__ Cb, const float* __restrict__ bias,
    const int* __restrict__ tok, const int* __restrict__ counts, const int* __restrict__ offs,
    int e, int chunk, int N, int K){
    int cnt = counts[e];
    int rem = cnt - chunk*2048;
    int nb = blockIdx.x, mb = blockIdx.y;
    if (mb*128 >= rem) return;
    int Mloc = rem < 2048 ? rem : 2048;
    int slot0 = offs[e] + chunk*2048;
    int tid = threadIdx.x, lane = tid & 63, w = tid >> 6;
    int rr = lane & 15, hi = lane >> 4;
    int wm = (w >> 1)*64, wn = (w & 1)*64;
    __shared__ u16 As[128*64];
    __shared__ u16 Bs[128*64];
    int sw_r = (rr & 7) * 8;
    int ce = (((lane&7) ^ (lane>>3)))*8;
    const u16* aptr[4]; const u16* bptr[4];
    u16 *adst[4], *bdst[4];
    #pragma unroll
    for (int p=0;p<4;++p){
        int r = (w*4+p)*8 + (lane>>3);
        int lr = mb*128 + r;
        int lc = lr < Mloc ? lr : (Mloc-1);
        size_t arow = UP ? (size_t)tok[slot0 + lc] : (size_t)lc;
        aptr[p] = A  + arow*K + ce;
        bptr[p] = Bt + (size_t)(nb*128 + r)*K + ce;
        adst[p] = &As[(w*4+p)*512];
        bdst[p] = &Bs[(w*4+p)*512];
    }
    f32x4 acc[4][4];
    #pragma unroll
    for (int mt=0;mt<4;++mt)
        #pragma unroll
        for (int nt=0;nt<4;++nt) acc[mt][nt] = (f32x4){0.f,0.f,0.f,0.f};

    for (int k0=0; k0<K; k0+=64){
        #pragma unroll
        for (int p=0;p<4;++p){
            gload16(aptr[p] + k0, adst[p]);
            gload16(bptr[p] + k0, bdst[p]);
        }
        __syncthreads();
        #pragma unroll
        for (int kc=0;kc<2;++kc){
            int kk = (kc*32 + hi*8) ^ sw_r;
            bf16x8 af[4], bfv[4];
            #pragma unroll
            for (int mt=0;mt<4;++mt) af[mt]  = *(const bf16x8*)&As[(wm+mt*16+rr)*64 + kk];
            #pragma unroll
            for (int nt=0;nt<4;++nt) bfv[nt] = *(const bf16x8*)&Bs[(wn+nt*16+rr)*64 + kk];
            #pragma unroll
            for (int mt=0;mt<4;++mt)
                #pragma unroll
                for (int nt=0;nt<4;++nt)
                    acc[mt][nt] = __builtin_amdgcn_mfma_f32_16x16x32_bf16(af[mt], bfv[nt], acc[mt][nt], 0,0,0);
        }
        __syncthreads();
    }
    #pragma unroll
    for (int mt=0;mt<4;++mt){
        #pragma unroll
        for (int j=0;j<4;++j){
            int m = wm + mt*16 + hi*4 + j;
            int lr = mb*128 + m;
            if (lr >= Mloc) continue;
            size_t orow = UP ? (size_t)lr : (size_t)(slot0 + lr);
            #pragma unroll
            for (int nt=0;nt<4;++nt){
                int col = nb*128 + wn + nt*16 + rr;
                float v = acc[mt][nt][j];
                if (MODE == 0)      Cf[orow*N + col] = v;
                else if (MODE == 2) Cb[orow*N + col] = f2b(gelu_f(v + bias[col]));
            }
        }
    }
}

// ---------------- elementwise / transpose helpers ----------------
// hf = x (residual base) + split(x) in one pass
__global__ __launch_bounds__(256) void init_split(const float* __restrict__ x,
                                                  float* __restrict__ hf,
                                                  u16* __restrict__ oh, u16* __restrict__ ol, int n){
    int i = blockIdx.x*256 + threadIdx.x;
    if (i < n){
        float v = x[i];
        hf[i] = v;
        u16 h = f2b(v);
        oh[i] = h;
        ol[i] = f2b(v - b2f(h));
    }
}

__global__ __launch_bounds__(256) void split_cvt(const float* __restrict__ in,
                                                 u16* __restrict__ oh, u16* __restrict__ ol, int n){
    int i = blockIdx.x*256 + threadIdx.x;
    if (i < n){
        float v = in[i];
        u16 h = f2b(v);
        oh[i] = h;
        ol[i] = f2b(v - b2f(h));
    }
}

__global__ void transpose_cvt(const float* __restrict__ in, u16* __restrict__ out, int R, int C){
    __shared__ float t[32][33];
    int c0 = blockIdx.x*32, r0 = blockIdx.y*32;
    int tx = threadIdx.x, ty = threadIdx.y;
    #pragma unroll
    for (int i=0;i<4;++i) t[ty+i*8][tx] = in[(size_t)(r0+ty+i*8)*C + c0+tx];
    __syncthreads();
    #pragma unroll
    for (int i=0;i<4;++i) out[(size_t)(c0+ty+i*8)*R + r0+tx] = f2b(t[tx][ty+i*8]);
}

__global__ void transpose_cvt_z(const float* __restrict__ in, u16* __restrict__ out, int R, int C,
                                size_t inzs, size_t outzs){
    in += (size_t)blockIdx.z * inzs;
    out += (size_t)blockIdx.z * outzs;
    __shared__ float t[32][33];
    int c0 = blockIdx.x*32, r0 = blockIdx.y*32;
    int tx = threadIdx.x, ty = threadIdx.y;
    #pragma unroll
    for (int i=0;i<4;++i) t[ty+i*8][tx] = in[(size_t)(r0+ty+i*8)*C + c0+tx];
    __syncthreads();
    #pragma unroll
    for (int i=0;i<4;++i) out[(size_t)(c0+ty+i*8)*R + r0+tx] = f2b(t[tx][ty+i*8]);
}

__global__ void transpose_split(const float* __restrict__ in, u16* __restrict__ oh,
                                u16* __restrict__ ol, int R, int C){
    __shared__ float t[32][33];
    int c0 = blockIdx.x*32, r0 = blockIdx.y*32;
    int tx = threadIdx.x, ty = threadIdx.y;
    #pragma unroll
    for (int i=0;i<4;++i) t[ty+i*8][tx] = in[(size_t)(r0+ty+i*8)*C + c0+tx];
    __syncthreads();
    #pragma unroll
    for (int i=0;i<4;++i){
        float v = t[tx][ty+i*8];
        size_t idx = (size_t)(c0+ty+i*8)*R + r0+tx;
        u16 h = f2b(v);
        oh[idx] = h;
        ol[idx] = f2b(v - b2f(h));
    }
}

__global__ void transpose_split_z(const float* __restrict__ in, u16* __restrict__ oh,
                                  u16* __restrict__ ol, int R, int C,
                                  size_t inzs, size_t outzs){
    in += (size_t)blockIdx.z * inzs;
    oh += (size_t)blockIdx.z * outzs;
    ol += (size_t)blockIdx.z * outzs;
    __shared__ float t[32][33];
    int c0 = blockIdx.x*32, r0 = blockIdx.y*32;
    int tx = threadIdx.x, ty = threadIdx.y;
    #pragma unroll
    for (int i=0;i<4;++i) t[ty+i*8][tx] = in[(size_t)(r0+ty+i*8)*C + c0+tx];
    __syncthreads();
    #pragma unroll
    for (int i=0;i<4;++i){
        float v = t[tx][ty+i*8];
        size_t idx = (size_t)(c0+ty+i*8)*R + r0+tx;
        u16 h = f2b(v);
        oh[idx] = h;
        ol[idx] = f2b(v - b2f(h));
    }
}

__global__ __launch_bounds__(256) void gelu_chunk(
    const float* __restrict__ Hef, const float* __restrict__ b1e,
    u16* __restrict__ oh, u16* __restrict__ ol,
    const int* __restrict__ counts, int e, int chunk){
    int row = blockIdx.x >> 4;
    int rem = counts[e] - chunk*2048;
    if (row >= rem) return;
    int i = blockIdx.x*256 + threadIdx.x;
    int n = i & 4095;
    float g = gelu_f(Hef[i] + b1e[n]);
    u16 h = f2b(g);
    oh[i] = h;
    ol[i] = f2b(g - b2f(h));
}

// combine; optionally also emit bf16 snapshot xb of the updated hidden state
__global__ __launch_bounds__(256) void combine_kernel(
    float* __restrict__ hf, const float* __restrict__ Mo,
    const int* __restrict__ slA, const int* __restrict__ slB,
    const int* __restrict__ e0, const int* __restrict__ e1,
    const float* __restrict__ w0, const float* __restrict__ w1,
    const float* __restrict__ b2l, u16* __restrict__ xbout){
    int t = blockIdx.x;
    int n = threadIdx.x*4;
    int sA = slA[t], sB = slB[t];
    const float* bA = b2l + e0[t]*1024;
    const float* bB = b2l + e1[t]*1024;
    float ww0 = w0[t], ww1 = w1[t];
    const float* pA = Mo + (size_t)sA*1024 + n;
    const float* pB = Mo + (size_t)sB*1024 + n;
    float* yp = hf + (size_t)t*1024 + n;
    u16* xp = xbout ? (xbout + (size_t)t*1024 + n) : nullptr;
    #pragma unroll
    for (int k=0;k<4;++k){
        float v = yp[k] + (pA[k] + bA[n+k])*ww0 + (pB[k] + bB[n+k])*ww1;
        yp[k] = v;
        if (xbout) xp[k] = f2b(v);
    }
}

__global__ __launch_bounds__(256) void qknorm_out(
    const float* __restrict__ qkvf, const float* __restrict__ qs, const float* __restrict__ ks,
    u16* __restrict__ qh, u16* __restrict__ ql, u16* __restrict__ kh, u16* __restrict__ kl,
    int split){
    int t = blockIdx.x*4 + (threadIdx.x>>6);
    int lane = threadIdx.x & 63;
    int h = lane>>2, d0 = (lane&3)*16;
    int b = t>>11, s = t & 2047;
    const float* qp = qkvf + (size_t)t*3072 + h*64 + d0;
    const float* kp = qp + 1024;
    float qv[16], kv[16];
    float sq = 0.f, sk = 0.f;
    #pragma unroll
    for (int i=0;i<16;++i){
        qv[i] = qp[i]; kv[i] = kp[i];
        sq += qv[i]*qv[i];  sk += kv[i]*kv[i];
    }
    sq += __shfl_xor(sq,1); sq += __shfl_xor(sq,2);
    sk += __shfl_xor(sk,1); sk += __shfl_xor(sk,2);
    float rq = rsqrtf(sq + 1e-6f) * 10.f;
    float rk = rsqrtf(sk + 1e-6f);
    size_t ob = ((size_t)(b*16+h)*2048 + s)*64 + d0;
    #pragma unroll
    for (int i=0;i<16;++i){
        float qn = qv[i]*rq*qs[d0+i];
        float kn = kv[i]*rk*ks[d0+i];
        u16 hq = f2b(qn), hk = f2b(kn);
        qh[ob+i] = hq; kh[ob+i] = hk;
        if (split){
            ql[ob+i] = f2b(qn - b2f(hq));
            kl[ob+i] = f2b(kn - b2f(hk));
        }
    }
}

__global__ void transpose_v(const float* __restrict__ qkvf, u16* __restrict__ vh,
                            u16* __restrict__ vl, int split){
    __shared__ float t[32][33];
    int s0 = blockIdx.x*32, d0 = blockIdx.y*32;
    int bh = blockIdx.z, b = bh>>4, h = bh&15;
    int tx = threadIdx.x, ty = threadIdx.y;
    #pragma unroll
    for (int i=0;i<4;++i)
        t[ty+i*8][tx] = qkvf[(size_t)(b*2048 + s0+ty+i*8)*3072 + 2048 + h*64 + d0 + tx];
    __syncthreads();
    #pragma unroll
    for (int i=0;i<4;++i){
        float v = t[tx][ty+i*8];
        size_t idx = ((size_t)bh*64 + d0+ty+i*8)*2048 + s0 + tx;
        u16 hv = f2b(v);
        vh[idx] = hv;
        if (split) vl[idx] = f2b(v - b2f(hv));
    }
}

// ---------------- MFMA flash attention (causal); bf16 hi(/lo) out ----------------
template<int SPLIT>
__global__ __launch_bounds__(256) void attn_flash(
    const u16* __restrict__ qh, const u16* __restrict__ ql,
    const u16* __restrict__ kh, const u16* __restrict__ kl,
    const u16* __restrict__ vth, const u16* __restrict__ vtl,
    u16* __restrict__ oh, u16* __restrict__ ol){
    int qt = blockIdx.x, bh = blockIdx.y;
    int tid = threadIdx.x, w = tid>>6, lane = tid & 63;
    int rr = lane & 15, hi = lane >> 4;
    __shared__ u16 Ksh[64*64];
    __shared__ u16 Vsh[64*64];
    __shared__ u16 Ksl[SPLIT ? 64*64 : 8];
    __shared__ u16 Vsl[SPLIT ? 64*64 : 8];
    __shared__ u16 Ps [4][16*72];
    __shared__ u16 Psl[SPLIT ? 4 : 1][16*72];
    int sw_w = ((tid>>3)&7)*8;
    int sw_r = (rr&7)*8;

    bf16x8 qfh[2], qfl[2];
    {
        size_t qo = (((size_t)bh*2048) + qt*64 + w*16 + rr)*64 + hi*8;
        qfh[0] = *(const bf16x8*)(qh + qo);
        qfh[1] = *(const bf16x8*)(qh + qo + 32);
        if (SPLIT){
            qfl[0] = *(const bf16x8*)(ql + qo);
            qfl[1] = *(const bf16x8*)(ql + qo + 32);
        }
    }
    f32x4 oacc[4];
    #pragma unroll
    for (int dt=0;dt<4;++dt) oacc[dt] = (f32x4){0.f,0.f,0.f,0.f};
    float mrow[4] = {-3e38f,-3e38f,-3e38f,-3e38f};
    float lrow[4] = {0.f,0.f,0.f,0.f};

    for (int kt=0; kt<=qt; ++kt){
        #pragma unroll
        for (int p=0;p<2;++p){
            int el = tid*8 + p*2048;
            int r = el>>6, c = el&63;
            int csw = c ^ sw_w;
            size_t koff = (((size_t)bh*2048) + kt*64 + r)*64 + c;
            size_t voff = ((size_t)bh*64 + r)*2048 + kt*64 + c;
            *(bf16x8*)&Ksh[r*64 + csw] = *(const bf16x8*)(kh + koff);
            *(bf16x8*)&Vsh[r*64 + csw] = *(const bf16x8*)(vth + voff);
            if (SPLIT){
                *(bf16x8*)&Ksl[r*64 + csw] = *(const bf16x8*)(kl + koff);
                *(bf16x8*)&Vsl[r*64 + csw] = *(const bf16x8*)(vtl + voff);
            }
        }
        __syncthreads();
        f32x4 sacc[4];
        #pragma unroll
        for (int nt=0;nt<4;++nt) sacc[nt] = (f32x4){0.f,0.f,0.f,0.f};
        #pragma unroll
        for (int kc=0;kc<2;++kc){
            int kk = (kc*32 + hi*8) ^ sw_r;
            #pragma unroll
            for (int nt=0;nt<4;++nt){
                bf16x8 kf = *(const bf16x8*)&Ksh[(nt*16+rr)*64 + kk];
                sacc[nt] = __builtin_amdgcn_mfma_f32_16x16x32_bf16(qfh[kc], kf, sacc[nt], 0,0,0);
                if (SPLIT){
                    bf16x8 kf2 = *(const bf16x8*)&Ksl[(nt*16+rr)*64 + kk];
                    sacc[nt] = __builtin_amdgcn_mfma_f32_16x16x32_bf16(qfh[kc], kf2, sacc[nt], 0,0,0);
                    sacc[nt] = __builtin_amdgcn_mfma_f32_16x16x32_bf16(qfl[kc], kf,  sacc[nt], 0,0,0);
                }
            }
        }
        if (kt == qt){
            #pragma unroll
            for (int nt=0;nt<4;++nt)
                #pragma unroll
                for (int j=0;j<4;++j)
                    if (nt*16 + rr > w*16 + hi*4 + j) sacc[nt][j] = -3e38f;
        }
        float corr[4];
        #pragma unroll
        for (int j=0;j<4;++j){
            float t = fmaxf(fmaxf(sacc[0][j],sacc[1][j]), fmaxf(sacc[2][j],sacc[3][j]));
            t = fmaxf(t, __shfl_xor(t,1));
            t = fmaxf(t, __shfl_xor(t,2));
            t = fmaxf(t, __shfl_xor(t,4));
            t = fmaxf(t, __shfl_xor(t,8));
            float mn = fmaxf(mrow[j], t);
            corr[j] = __expf(mrow[j] - mn);
            mrow[j] = mn;
        }
        float rsum[4] = {0.f,0.f,0.f,0.f};
        #pragma unroll
        for (int nt=0;nt<4;++nt)
            #pragma unroll
            for (int j=0;j<4;++j){
                float p = __expf(sacc[nt][j] - mrow[j]);
                sacc[nt][j] = p;
                rsum[j] += p;
            }
        #pragma unroll
        for (int j=0;j<4;++j){
            rsum[j] += __shfl_xor(rsum[j],1);
            rsum[j] += __shfl_xor(rsum[j],2);
            rsum[j] += __shfl_xor(rsum[j],4);
            rsum[j] += __shfl_xor(rsum[j],8);
            lrow[j] = lrow[j]*corr[j] + rsum[j];
        }
        #pragma unroll
        for (int dt=0;dt<4;++dt)
            #pragma unroll
            for (int j=0;j<4;++j) oacc[dt][j] *= corr[j];
        u16* pw = Ps[w];
        #pragma unroll
        for (int nt=0;nt<4;++nt)
            #pragma unroll
            for (int j=0;j<4;++j){
                float p = sacc[nt][j];
                u16 ph = f2b(p);
                pw[(hi*4+j)*72 + nt*16 + rr] = ph;
                if (SPLIT) Psl[w][(hi*4+j)*72 + nt*16 + rr] = f2b(p - b2f(ph));
            }
        __syncthreads();
        #pragma unroll
        for (int kc=0;kc<2;++kc){
            bf16x8 pf = *(const bf16x8*)&pw[rr*72 + kc*32 + hi*8];
            bf16x8 pfl;
            if (SPLIT) pfl = *(const bf16x8*)&Psl[w][rr*72 + kc*32 + hi*8];
            int vk = (kc*32 + hi*8) ^ sw_r;
            #pragma unroll
            for (int dt=0;dt<4;++dt){
                bf16x8 vf = *(const bf16x8*)&Vsh[(dt*16+rr)*64 + vk];
                oacc[dt] = __builtin_amdgcn_mfma_f32_16x16x32_bf16(pf, vf, oacc[dt], 0,0,0);
                if (SPLIT){
                    bf16x8 vf2 = *(const bf16x8*)&Vsl[(dt*16+rr)*64 + vk];
                    oacc[dt] = __builtin_amdgcn_mfma_f32_16x16x32_bf16(pf,  vf2, oacc[dt], 0,0,0);
                    oacc[dt] = __builtin_amdgcn_mfma_f32_16x16x32_bf16(pfl, vf,  oacc[dt], 0,0,0);
                }
            }
        }
        __syncthreads();
    }
    int b = bh>>4, h = bh&15;
    #pragma unroll
    for (int j=0;j<4;++j){
        float inv = 1.f/lrow[j];
        int srow = qt*64 + w*16 + hi*4 + j;
        size_t obase = ((size_t)b*2048 + srow)*1024 + h*64;
        #pragma unroll
        for (int dt=0;dt<4;++dt){
            float v = oacc[dt][j]*inv;
            u16 hh = f2b(v);
            oh[obase + dt*16 + rr] = hh;
            if (SPLIT) ol[obase + dt*16 + rr] = f2b(v - b2f(hh));
        }
    }
}

// ---------------- gating + routing (verified r17) ----------------
__global__ __launch_bounds__(256) void gating_top2(
    const float* __restrict__ h, const float* __restrict__ Wg,
    int* __restrict__ e0, int* __restrict__ e1,
    float* __restrict__ w0, float* __restrict__ w1){
    int t = blockIdx.x*4 + (threadIdx.x>>6);
    int lane = threadIdx.x & 63;
    const float* xr = h + (size_t)t*1024;
    float s[8] = {0,0,0,0,0,0,0,0};
    #pragma unroll
    for (int i=0;i<16;++i){
        int d = lane*16 + i;
        float xv = xr[d];
        const float* wr = Wg + d*8;
        #pragma unroll
        for (int ee=0;ee<8;++ee) s[ee] += xv * wr[ee];
    }
    #pragma unroll
    for (int off=1;off<64;off<<=1){
        #pragma unroll
        for (int ee=0;ee<8;++ee) s[ee] += __shfl_xor(s[ee], off);
    }
    if (lane == 0){
        int b0 = 0; float v0 = s[0];
        #pragma unroll
        for (int ee=1;ee<8;++ee) if (s[ee] > v0){ v0 = s[ee]; b0 = ee; }
        int b1i = -1; float v1 = -3e38f;
        #pragma unroll
        for (int ee=0;ee<8;++ee) if (ee != b0 && s[ee] > v1){ v1 = s[ee]; b1i = ee; }
        float z = __expf(v1 - v0);
        float inv = 1.f/(1.f + z);
        e0[t] = b0; e1[t] = b1i; w0[t] = inv; w1[t] = z*inv;
    }
}

__global__ __launch_bounds__(512) void routing_kernel(
    const int* __restrict__ e0, const int* __restrict__ e1,
    int* __restrict__ tok, int* __restrict__ slotA, int* __restrict__ slotB,
    int* __restrict__ counts, int* __restrict__ offs){
    int w = threadIdx.x>>6, lane = threadIdx.x & 63;
    __shared__ int soff[8];
    unsigned long long below = (1ull << lane) - 1ull;
    int c = 0;
    for (int base=0; base<4096; base+=64){
        int t = base + lane;
        bool f = (e0[t]==w) | (e1[t]==w);
        c += __popcll(__ballot(f));
    }
    if (lane == 0) soff[w] = c;
    __syncthreads();
    if (threadIdx.x == 0){
        int r = 0;
        for (int i=0;i<8;++i){ int ci = soff[i]; counts[i] = ci; offs[i] = r; soff[i] = r; r += ci; }
    }
    __syncthreads();
    int run = soff[w];
    for (int base=0; base<4096; base+=64){
        int t = base + lane;
        bool f0 = (e0[t]==w), f1 = (e1[t]==w);
        bool f = f0 | f1;
        unsigned long long m = __ballot(f);
        int pos = __popcll(m & below);
        if (f){
            int sl = run + pos;
            tok[sl] = t;
            if (f0) slotA[t] = sl; else slotB[t] = sl;
        }
        run += __popcll(m);
    }
}

// ---------------- launcher ----------------
extern "C" void kernel_launch(void* const* d_in, const int* in_sizes, int n_in,
                              void* d_out, int out_size, void* d_ws, size_t ws_size,
                              hipStream_t stream){
    const float* x  = (const float*)d_in[0];
    const float* Wq = (const float*)d_in[1];
    const float* Wk = (const float*)d_in[2];
    const float* Wv = (const float*)d_in[3];
    const float* Wo = (const float*)d_in[4];
    const float* qs = (const float*)d_in[5];
    const float* ks = (const float*)d_in[6];
    const float* Wg = (const float*)d_in[7];
    const float* W1 = (const float*)d_in[8];
    const float* b1 = (const float*)d_in[9];
    const float* W2 = (const float*)d_in[10];
    const float* b2 = (const float*)d_in[11];

    char* base = (char*)d_ws;
    const size_t MB = 1024*1024;
    const bool big = ws_size >= (size_t)470*MB;

    float* qkvf = (float*)base;                // 0-48  (attn phase)
    float* Mo   = (float*)base;                // MoE: 0-32
    float* Hef  = (float*)(base + 32*MB);      // fallback MoE: 32-64
    u16*   He16f= (u16*)  (base + 32*MB);      // fallback L1 MoE
    u16*   afhi = (u16*)  (base + 48*MB);      // 48-56  attn out hi (bf16)
    u16*   aflo = (u16*)  (base + 56*MB);      // 56-64  attn out lo
    u16*   qhbh = (u16*)  (base + 64*MB);
    u16*   khbh = (u16*)  (base + 72*MB);
    u16*   vtbh = (u16*)  (base + 80*MB);
    u16*   qhbl = (u16*)  (base + 88*MB);
    u16*   khbl = (u16*)  (base + 96*MB);
    u16*   vtbl = (u16*)  (base + 104*MB);
    u16*   HeHic= (u16*)  (base + 64*MB);      // fallback chunk bufs
    u16*   HeLoc= (u16*)  (base + 80*MB);
    u16*   xhi  = (u16*)  (base + 112*MB);
    u16*   xlo  = (u16*)  (base + 120*MB);
    u16*   xb   = (u16*)  (base + 128*MB);
    u16*   wTh  = (u16*)  (base + 136*MB);
    u16*   wTl  = (u16*)  (base + 144*MB);
    u16*   w2Th = (u16*)  (base + 152*MB);
    u16*   w2Tl = (u16*)  (base + 160*MB);
    // big-path MoE regions
    u16*   W1Th = (u16*)  (base + 32*MB);      // 32-96
    u16*   W1Tl = (u16*)  (base + 136*MB);     // 136-200
    u16*   W2Thb= (u16*)  (base + 200*MB);     // 200-264
    u16*   W2Tlb= (u16*)  (base + 264*MB);     // 264-328
    u16*   HeH  = (u16*)  (base + 328*MB);     // 328-392
    u16*   HeL  = (u16*)  (base + 392*MB);     // 392-456
    u16*   He16g= (u16*)  (base + 200*MB);     // big L1 W2T
    // routing data
    char*  rbase = base + (big ? (size_t)458*MB : (size_t)168*MB);
    int*   e0b  = (int*)  rbase;
    int*   e1b  = e0b + 4096;
    float* w0b  = (float*)(e1b + 4096);
    float* w1b  = w0b + 4096;
    int*   tok  = (int*)(w1b + 4096);
    int*   slA  = tok + 8192;
    int*   slB  = slA + 4096;
    int*   cnts = slB + 4096;
    int*   offs = cnts + 8;

    float* hf = (float*)d_out;
    const size_t HTOK = (size_t)4096*1024;

    const size_t WSTRIDE = (size_t)1024*1024;
    const size_t ESTRIDE = (size_t)1024*4096;

    // =================== LAYER 0 (split-bf16: fp32-grade h1) ===================
    {
        init_split<<<16384,256,0,stream>>>(x, hf, xhi, xlo, (int)HTOK);
        gating_top2<<<1024,256,0,stream>>>(hf, Wg, e0b,e1b,w0b,w1b);
        routing_kernel<<<1,512,0,stream>>>(e0b,e1b, tok,slA,slB, cnts,offs);

        transpose_split<<<dim3(32,32),dim3(32,8),0,stream>>>(Wq, wTh,           wTl,           1024,1024);
        transpose_split<<<dim3(32,32),dim3(32,8),0,stream>>>(Wk, wTh + 1048576, wTl + 1048576, 1024,1024);
        transpose_split<<<dim3(32,32),dim3(32,8),0,stream>>>(Wv, wTh + 2097152, wTl + 2097152, 1024,1024);
        mgemm_s<0><<<dim3(24,32),256,0,stream>>>(xhi, xlo, wTh, wTl, qkvf, 4096,3072,1024,3072);

        qknorm_out<<<1024,256,0,stream>>>(qkvf, qs, ks, qhbh, qhbl, khbh, khbl, 1);
        transpose_v<<<dim3(64,2,32),dim3(32,8),0,stream>>>(qkvf, vtbh, vtbl, 1);
        attn_flash<1><<<dim3(32,32),256,0,stream>>>(qhbh, qhbl, khbh, khbl, vtbh, vtbl, afhi, aflo);

        transpose_split<<<dim3(32,32),dim3(32,8),0,stream>>>(Wo, w2Th, w2Tl, 1024,1024);
        mgemm_s<1><<<dim3(8,32),256,0,stream>>>(afhi, aflo, w2Th, w2Tl, hf, 4096,1024,1024,1024);

        if (big){
            transpose_split_z<<<dim3(128,32,8),dim3(32,8),0,stream>>>(W1, W1Th, W1Tl, 1024,4096, ESTRIDE, (size_t)4096*1024);
            transpose_split_z<<<dim3(32,128,8),dim3(32,8),0,stream>>>(W2, W2Thb, W2Tlb, 4096,1024, ESTRIDE, (size_t)1024*4096);
            mgemm_gs<true ><<<dim3(32,32,8),256,0,stream>>>(xhi, xlo, W1Th, W1Tl, nullptr, HeH, HeL, b1, tok,cnts,offs, 4096,1024);
            mgemm_gs<false><<<dim3(32,8,8),256,0,stream>>>(HeH, HeL, W2Thb, W2Tlb, Mo, nullptr,nullptr, nullptr, tok,cnts,offs, 1024,4096);
        } else {
            for (int e=0; e<8; ++e){
                const float* W1e = W1 + (size_t)e*ESTRIDE;
                const float* W2e = W2 + (size_t)e*ESTRIDE;
                const float* b1e = b1 + (size_t)e*4096;
                transpose_split<<<dim3(128,32),dim3(32,8),0,stream>>>(W1e, wTh,  wTl,  1024,4096);
                transpose_split<<<dim3(32,128),dim3(32,8),0,stream>>>(W2e, w2Th, w2Tl, 4096,1024);
                for (int c=0; c<2; ++c){
                    mgemm_xs<true ><<<dim3(32,16),256,0,stream>>>(xhi, xlo, wTh, wTl, Hef, tok,cnts,offs, e,c, 4096,1024);
                    gelu_chunk<<<32768,256,0,stream>>>(Hef, b1e, HeHic, HeLoc, cnts, e, c);
                    mgemm_xs<false><<<dim3(8,16),256,0,stream>>>(HeHic, HeLoc, w2Th, w2Tl, Mo, tok,cnts,offs, e,c, 1024,4096);
                }
            }
        }
        combine_kernel<<<4096,256,0,stream>>>(hf, Mo, slA,slB, e0b,e1b, w0b,w1b, b2, xb);
    }

    // =================== LAYER 1 (plain bf16) ===================
    {
        gating_top2<<<1024,256,0,stream>>>(hf, Wg + (size_t)1024*8, e0b,e1b,w0b,w1b);
        routing_kernel<<<1,512,0,stream>>>(e0b,e1b, tok,slA,slB, cnts,offs);

        transpose_cvt<<<dim3(32,32),dim3(32,8),0,stream>>>(Wq + WSTRIDE, wTh,           1024,1024);
        transpose_cvt<<<dim3(32,32),dim3(32,8),0,stream>>>(Wk + WSTRIDE, wTh + 1048576, 1024,1024);
        transpose_cvt<<<dim3(32,32),dim3(32,8),0,stream>>>(Wv + WSTRIDE, wTh + 2097152, 1024,1024);
        mgemm<0><<<dim3(24,32),256,0,stream>>>(xb, wTh, qkvf, nullptr, nullptr,nullptr, 4096,3072,1024,3072);

        qknorm_out<<<1024,256,0,stream>>>(qkvf, qs + 64, ks + 64, qhbh, nullptr, khbh, nullptr, 0);
        transpose_v<<<dim3(64,2,32),dim3(32,8),0,stream>>>(qkvf, vtbh, nullptr, 0);
        attn_flash<0><<<dim3(32,32),256,0,stream>>>(qhbh, nullptr, khbh, nullptr, vtbh, nullptr, afhi, nullptr);

        transpose_cvt<<<dim3(32,32),dim3(32,8),0,stream>>>(Wo + WSTRIDE, w2Th, 1024,1024);
        mgemm<1><<<dim3(8,32),256,0,stream>>>(afhi, w2Th, hf, nullptr, nullptr,nullptr, 4096,1024,1024,1024);

        if (big){
            transpose_cvt_z<<<dim3(128,32,8),dim3(32,8),0,stream>>>(W1 + (size_t)8*ESTRIDE, W1Th, 1024,4096, ESTRIDE, (size_t)4096*1024);
            transpose_cvt_z<<<dim3(32,128,8),dim3(32,8),0,stream>>>(W2 + (size_t)8*ESTRIDE, He16g, 4096,1024, ESTRIDE, (size_t)1024*4096);
            mgemm_gp<true ><<<dim3(32,32,8),256,0,stream>>>(xb, W1Th, nullptr, (u16*)HeH, b1 + (size_t)8*4096, tok,cnts,offs, 4096,1024);
            mgemm_gp<false><<<dim3(32,8,8),256,0,stream>>>((u16*)HeH, He16g, Mo, nullptr, nullptr, tok,cnts,offs, 1024,4096);
        } else {
            for (int e=0; e<8; ++e){
                const float* W1e = W1 + (size_t)(8 + e)*ESTRIDE;
                const float* W2e = W2 + (size_t)(8 + e)*ESTRIDE;
                const float* b1e = b1 + (size_t)(8 + e)*4096;
                transpose_cvt<<<dim3(128,32),dim3(32,8),0,stream>>>(W1e, wTh,  1024,4096);
                transpose_cvt<<<dim3(32,128),dim3(32,8),0,stream>>>(W2e, w2Th, 4096,1024);
                for (int c=0; c<2; ++c){
                    mgemm_x<2,true ><<<dim3(32,16),256,0,stream>>>(xb, wTh, nullptr, He16f, b1e, tok,cnts,offs, e,c, 4096,1024);
                    mgemm_x<0,false><<<dim3(8,16),256,0,stream>>>(He16f, w2Th, Mo, nullptr, nullptr, tok,cnts,offs, e,c, 1024,4096);
                }
            }
        }
        combine_kernel<<<4096,256,0,stream>>>(hf, Mo, slA,slB, e0b,e1b, w0b,w1b, b2 + (size_t)8*1024, nullptr);
    }
}

// Round 22
// 1935.899 us; speedup vs baseline: 1.7767x; 1.7767x over previous
//
#include <hip/hip_runtime.h>
#include <cstdint>

typedef unsigned short u16;
typedef __attribute__((ext_vector_type(4))) float f32x4;
typedef __attribute__((ext_vector_type(8))) __bf16 bf16x8;

#define DEV static __device__ __forceinline__

DEV u16 f2b(float f){
    unsigned int u = __builtin_bit_cast(unsigned int, f);
    u += 0x7fffu + ((u >> 16) & 1u);
    return (u16)(u >> 16);
}
DEV float b2f(u16 u){ return __builtin_bit_cast(float, (unsigned int)u << 16); }
DEV float gelu_f(float x){
    float x3 = x*x*x;
    return 0.5f*x*(1.f + tanhf(0.7978845608f*(x + 0.044715f*x3)));
}

DEV void gload16(const u16* g, u16* l){
    __builtin_amdgcn_global_load_lds(
        (const __attribute__((address_space(1))) unsigned int*)g,
        (__attribute__((address_space(3))) unsigned int*)l,
        16, 0, 0);
}

// ---------------- MFMA GEMM plain (verified) ----------------
template<int MODE>
__global__ __launch_bounds__(256) void mgemm(
    const u16* __restrict__ A, const u16* __restrict__ Bt,
    float* __restrict__ Cf, u16* __restrict__ Cb,
    const float* __restrict__ bias, const float* __restrict__ rowscale,
    int M, int N, int K, int ldc){
    int nb = blockIdx.x, mb = blockIdx.y;
    int tid = threadIdx.x, lane = tid & 63, w = tid >> 6;
    int rr = lane & 15, hi = lane >> 4;
    int wm = (w >> 1)*64, wn = (w & 1)*64;
    __shared__ u16 As[128*64];
    __shared__ u16 Bs[128*64];
    int sw_r = (rr & 7) * 8;
    int ce = (((lane&7) ^ (lane>>3)))*8;
    const u16* ap[4]; const u16* bp[4];
    u16* adst[4]; u16* bdst[4];
    #pragma unroll
    for (int p=0;p<4;++p){
        int r = (w*4+p)*8 + (lane>>3);
        ap[p] = A  + (size_t)(mb*128 + r)*K + ce;
        bp[p] = Bt + (size_t)(nb*128 + r)*K + ce;
        adst[p] = &As[(w*4+p)*512];
        bdst[p] = &Bs[(w*4+p)*512];
    }
    f32x4 acc[4][4];
    #pragma unroll
    for (int mt=0;mt<4;++mt)
        #pragma unroll
        for (int nt=0;nt<4;++nt) acc[mt][nt] = (f32x4){0.f,0.f,0.f,0.f};

    for (int k0=0; k0<K; k0+=64){
        #pragma unroll
        for (int p=0;p<4;++p){
            gload16(ap[p] + k0, adst[p]);
            gload16(bp[p] + k0, bdst[p]);
        }
        __syncthreads();
        #pragma unroll
        for (int kc=0;kc<2;++kc){
            int kk = (kc*32 + hi*8) ^ sw_r;
            bf16x8 af[4], bfv[4];
            #pragma unroll
            for (int mt=0;mt<4;++mt) af[mt]  = *(const bf16x8*)&As[(wm+mt*16+rr)*64 + kk];
            #pragma unroll
            for (int nt=0;nt<4;++nt) bfv[nt] = *(const bf16x8*)&Bs[(wn+nt*16+rr)*64 + kk];
            #pragma unroll
            for (int mt=0;mt<4;++mt)
                #pragma unroll
                for (int nt=0;nt<4;++nt)
                    acc[mt][nt] = __builtin_amdgcn_mfma_f32_16x16x32_bf16(af[mt], bfv[nt], acc[mt][nt], 0,0,0);
        }
        __syncthreads();
    }
    #pragma unroll
    for (int mt=0;mt<4;++mt){
        #pragma unroll
        for (int j=0;j<4;++j){
            int m = wm + mt*16 + hi*4 + j;
            size_t orow = (size_t)(mb*128 + m);
            #pragma unroll
            for (int nt=0;nt<4;++nt){
                int col = nb*128 + wn + nt*16 + rr;
                float v = acc[mt][nt][j];
                if (MODE == 0)      Cf[orow*ldc + col] = v;
                else if (MODE == 1) Cf[orow*ldc + col] += v;
            }
        }
    }
}

// ---------------- FUSED split-bf16 GEMM (dense, verified) ----------------
template<int MODE>
__global__ __launch_bounds__(256) void mgemm_s(
    const u16* __restrict__ Ah, const u16* __restrict__ Al,
    const u16* __restrict__ Bth, const u16* __restrict__ Btl,
    float* __restrict__ Cf, int M, int N, int K, int ldc){
    int nb = blockIdx.x, mb = blockIdx.y;
    int tid = threadIdx.x, lane = tid & 63, w = tid >> 6;
    int rr = lane & 15, hi = lane >> 4;
    int wm = (w >> 1)*64, wn = (w & 1)*64;
    __shared__ u16 Ash[128*64];
    __shared__ u16 Asl[128*64];
    __shared__ u16 Bsh[128*64];
    __shared__ u16 Bsl[128*64];
    int sw_r = (rr & 7) * 8;
    int ce = (((lane&7) ^ (lane>>3)))*8;
    const u16* ahp[4]; const u16* alp[4]; const u16* bhp[4]; const u16* blp[4];
    u16 *ahd[4], *ald[4], *bhd[4], *bld[4];
    #pragma unroll
    for (int p=0;p<4;++p){
        int r = (w*4+p)*8 + (lane>>3);
        size_t ao = (size_t)(mb*128 + r)*K + ce;
        size_t bo = (size_t)(nb*128 + r)*K + ce;
        ahp[p] = Ah + ao;  alp[p] = Al + ao;
        bhp[p] = Bth + bo; blp[p] = Btl + bo;
        ahd[p] = &Ash[(w*4+p)*512]; ald[p] = &Asl[(w*4+p)*512];
        bhd[p] = &Bsh[(w*4+p)*512]; bld[p] = &Bsl[(w*4+p)*512];
    }
    f32x4 acc[4][4];
    #pragma unroll
    for (int mt=0;mt<4;++mt)
        #pragma unroll
        for (int nt=0;nt<4;++nt) acc[mt][nt] = (f32x4){0.f,0.f,0.f,0.f};

    for (int k0=0; k0<K; k0+=64){
        #pragma unroll
        for (int p=0;p<4;++p){
            gload16(ahp[p] + k0, ahd[p]);
            gload16(alp[p] + k0, ald[p]);
            gload16(bhp[p] + k0, bhd[p]);
            gload16(blp[p] + k0, bld[p]);
        }
        __syncthreads();
        #pragma unroll
        for (int kc=0;kc<2;++kc){
            int kk = (kc*32 + hi*8) ^ sw_r;
            bf16x8 afh[4], afl[4], bfh[4], bfl[4];
            #pragma unroll
            for (int mt=0;mt<4;++mt){
                afh[mt] = *(const bf16x8*)&Ash[(wm+mt*16+rr)*64 + kk];
                afl[mt] = *(const bf16x8*)&Asl[(wm+mt*16+rr)*64 + kk];
            }
            #pragma unroll
            for (int nt=0;nt<4;++nt){
                bfh[nt] = *(const bf16x8*)&Bsh[(wn+nt*16+rr)*64 + kk];
                bfl[nt] = *(const bf16x8*)&Bsl[(wn+nt*16+rr)*64 + kk];
            }
            #pragma unroll
            for (int mt=0;mt<4;++mt)
                #pragma unroll
                for (int nt=0;nt<4;++nt){
                    acc[mt][nt] = __builtin_amdgcn_mfma_f32_16x16x32_bf16(afh[mt], bfh[nt], acc[mt][nt], 0,0,0);
                    acc[mt][nt] = __builtin_amdgcn_mfma_f32_16x16x32_bf16(afh[mt], bfl[nt], acc[mt][nt], 0,0,0);
                    acc[mt][nt] = __builtin_amdgcn_mfma_f32_16x16x32_bf16(afl[mt], bfh[nt], acc[mt][nt], 0,0,0);
                }
        }
        __syncthreads();
    }
    #pragma unroll
    for (int mt=0;mt<4;++mt){
        #pragma unroll
        for (int j=0;j<4;++j){
            int m = wm + mt*16 + hi*4 + j;
            size_t orow = (size_t)(mb*128 + m);
            #pragma unroll
            for (int nt=0;nt<4;++nt){
                int col = nb*128 + wn + nt*16 + rr;
                float v = acc[mt][nt][j];
                if (MODE == 0)      Cf[orow*ldc + col] = v;
                else if (MODE == 1) Cf[orow*ldc + col] += v;
            }
        }
    }
}

// ---------------- GROUPED split expert GEMM (r20 grid order: nb = blockIdx.x) ----------------
template<bool UP>
__global__ __launch_bounds__(256) void mgemm_gs(
    const u16* __restrict__ Ah, const u16* __restrict__ Al,
    const u16* __restrict__ Bth, const u16* __restrict__ Btl,
    float* __restrict__ Cf, u16* __restrict__ OutH, u16* __restrict__ OutL,
    const float* __restrict__ b1all,
    const int* __restrict__ tok, const int* __restrict__ counts, const int* __restrict__ offs,
    int N, int K){
    int e = blockIdx.z;
    int cnt = counts[e];
    int nb = blockIdx.x, mb = blockIdx.y;
    if (mb*128 >= cnt) return;
    int slot0 = offs[e];
    const u16* Bh = Bth + (size_t)e*N*K;
    const u16* Bl = Btl + (size_t)e*N*K;
    int tid = threadIdx.x, lane = tid & 63, w = tid >> 6;
    int rr = lane & 15, hi = lane >> 4;
    int wm = (w >> 1)*64, wn = (w & 1)*64;
    __shared__ u16 Ash[128*64];
    __shared__ u16 Asl[128*64];
    __shared__ u16 Bsh[128*64];
    __shared__ u16 Bsl[128*64];
    int sw_r = (rr & 7) * 8;
    int ce = (((lane&7) ^ (lane>>3)))*8;
    const u16* ahp[4]; const u16* alp[4]; const u16* bhp[4]; const u16* blp[4];
    u16 *ahd[4], *ald[4], *bhd[4], *bld[4];
    #pragma unroll
    for (int p=0;p<4;++p){
        int r = (w*4+p)*8 + (lane>>3);
        int lr = mb*128 + r;
        int lc = lr < cnt ? lr : (cnt-1);
        size_t arow = UP ? (size_t)tok[slot0 + lc] : (size_t)(slot0 + lc);
        ahp[p] = Ah + arow*K + ce;
        alp[p] = Al + arow*K + ce;
        bhp[p] = Bh + (size_t)(nb*128 + r)*K + ce;
        blp[p] = Bl + (size_t)(nb*128 + r)*K + ce;
        ahd[p] = &Ash[(w*4+p)*512]; ald[p] = &Asl[(w*4+p)*512];
        bhd[p] = &Bsh[(w*4+p)*512]; bld[p] = &Bsl[(w*4+p)*512];
    }
    f32x4 acc[4][4];
    #pragma unroll
    for (int mt=0;mt<4;++mt)
        #pragma unroll
        for (int nt=0;nt<4;++nt) acc[mt][nt] = (f32x4){0.f,0.f,0.f,0.f};

    for (int k0=0; k0<K; k0+=64){
        #pragma unroll
        for (int p=0;p<4;++p){
            gload16(ahp[p] + k0, ahd[p]);
            gload16(alp[p] + k0, ald[p]);
            gload16(bhp[p] + k0, bhd[p]);
            gload16(blp[p] + k0, bld[p]);
        }
        __syncthreads();
        #pragma unroll
        for (int kc=0;kc<2;++kc){
            int kk = (kc*32 + hi*8) ^ sw_r;
            bf16x8 afh[4], afl[4], bfh[4], bfl[4];
            #pragma unroll
            for (int mt=0;mt<4;++mt){
                afh[mt] = *(const bf16x8*)&Ash[(wm+mt*16+rr)*64 + kk];
                afl[mt] = *(const bf16x8*)&Asl[(wm+mt*16+rr)*64 + kk];
            }
            #pragma unroll
            for (int nt=0;nt<4;++nt){
                bfh[nt] = *(const bf16x8*)&Bsh[(wn+nt*16+rr)*64 + kk];
                bfl[nt] = *(const bf16x8*)&Bsl[(wn+nt*16+rr)*64 + kk];
            }
            #pragma unroll
            for (int mt=0;mt<4;++mt)
                #pragma unroll
                for (int nt=0;nt<4;++nt){
                    acc[mt][nt] = __builtin_amdgcn_mfma_f32_16x16x32_bf16(afh[mt], bfh[nt], acc[mt][nt], 0,0,0);
                    acc[mt][nt] = __builtin_amdgcn_mfma_f32_16x16x32_bf16(afh[mt], bfl[nt], acc[mt][nt], 0,0,0);
                    acc[mt][nt] = __builtin_amdgcn_mfma_f32_16x16x32_bf16(afl[mt], bfh[nt], acc[mt][nt], 0,0,0);
                }
        }
        __syncthreads();
    }
    const float* b1e = UP ? (b1all + (size_t)e*N) : nullptr;
    #pragma unroll
    for (int mt=0;mt<4;++mt){
        #pragma unroll
        for (int j=0;j<4;++j){
            int m = wm + mt*16 + hi*4 + j;
            int lr = mb*128 + m;
            if (lr >= cnt) continue;
            size_t orow = (size_t)(slot0 + lr);
            #pragma unroll
            for (int nt=0;nt<4;++nt){
                int col = nb*128 + wn + nt*16 + rr;
                float v = acc[mt][nt][j];
                if (UP){
                    float g = gelu_f(v + b1e[col]);
                    u16 h = f2b(g);
                    OutH[orow*N + col] = h;
                    OutL[orow*N + col] = f2b(g - b2f(h));
                } else {
                    Cf[orow*N + col] = v;
                }
            }
        }
    }
}

// ---------------- GROUPED plain expert GEMM (L1; r20 grid order) ----------------
template<bool UP>
__global__ __launch_bounds__(256) void mgemm_gp(
    const u16* __restrict__ A, const u16* __restrict__ Bt,
    float* __restrict__ Cf, u16* __restrict__ Cb, const float* __restrict__ b1all,
    const int* __restrict__ tok, const int* __restrict__ counts, const int* __restrict__ offs,
    int N, int K){
    int e = blockIdx.z;
    int cnt = counts[e];
    int nb = blockIdx.x, mb = blockIdx.y;
    if (mb*128 >= cnt) return;
    int slot0 = offs[e];
    const u16* Bte = Bt + (size_t)e*N*K;
    int tid = threadIdx.x, lane = tid & 63, w = tid >> 6;
    int rr = lane & 15, hi = lane >> 4;
    int wm = (w >> 1)*64, wn = (w & 1)*64;
    __shared__ u16 As[128*64];
    __shared__ u16 Bs[128*64];
    int sw_r = (rr & 7) * 8;
    int ce = (((lane&7) ^ (lane>>3)))*8;
    const u16* aptr[4]; const u16* bptr[4];
    u16 *adst[4], *bdst[4];
    #pragma unroll
    for (int p=0;p<4;++p){
        int r = (w*4+p)*8 + (lane>>3);
        int lr = mb*128 + r;
        int lc = lr < cnt ? lr : (cnt-1);
        size_t arow = UP ? (size_t)tok[slot0 + lc] : (size_t)(slot0 + lc);
        aptr[p] = A  + arow*K + ce;
        bptr[p] = Bte + (size_t)(nb*128 + r)*K + ce;
        adst[p] = &As[(w*4+p)*512];
        bdst[p] = &Bs[(w*4+p)*512];
    }
    f32x4 acc[4][4];
    #pragma unroll
    for (int mt=0;mt<4;++mt)
        #pragma unroll
        for (int nt=0;nt<4;++nt) acc[mt][nt] = (f32x4){0.f,0.f,0.f,0.f};

    for (int k0=0; k0<K; k0+=64){
        #pragma unroll
        for (int p=0;p<4;++p){
            gload16(aptr[p] + k0, adst[p]);
            gload16(bptr[p] + k0, bdst[p]);
        }
        __syncthreads();
        #pragma unroll
        for (int kc=0;kc<2;++kc){
            int kk = (kc*32 + hi*8) ^ sw_r;
            bf16x8 af[4], bfv[4];
            #pragma unroll
            for (int mt=0;mt<4;++mt) af[mt]  = *(const bf16x8*)&As[(wm+mt*16+rr)*64 + kk];
            #pragma unroll
            for (int nt=0;nt<4;++nt) bfv[nt] = *(const bf16x8*)&Bs[(wn+nt*16+rr)*64 + kk];
            #pragma unroll
            for (int mt=0;mt<4;++mt)
                #pragma unroll
                for (int nt=0;nt<4;++nt)
                    acc[mt][nt] = __builtin_amdgcn_mfma_f32_16x16x32_bf16(af[mt], bfv[nt], acc[mt][nt], 0,0,0);
        }
        __syncthreads();
    }
    const float* b1e = UP ? (b1all + (size_t)e*N) : nullptr;
    #pragma unroll
    for (int mt=0;mt<4;++mt){
        #pragma unroll
        for (int j=0;j<4;++j){
            int m = wm + mt*16 + hi*4 + j;
            int lr = mb*128 + m;
            if (lr >= cnt) continue;
            size_t orow = (size_t)(slot0 + lr);
            #pragma unroll
            for (int nt=0;nt<4;++nt){
                int col = nb*128 + wn + nt*16 + rr;
                float v = acc[mt][nt][j];
                if (UP) Cb[orow*N + col] = f2b(gelu_f(v + b1e[col]));
                else    Cf[orow*N + col] = v;
            }
        }
    }
}

// ---------------- elementwise / transpose helpers ----------------
__global__ __launch_bounds__(256) void init_split(const float* __restrict__ x,
                                                  float* __restrict__ hf,
                                                  u16* __restrict__ oh, u16* __restrict__ ol, int n){
    int i = blockIdx.x*256 + threadIdx.x;
    if (i < n){
        float v = x[i];
        hf[i] = v;
        u16 h = f2b(v);
        oh[i] = h;
        ol[i] = f2b(v - b2f(h));
    }
}

__global__ void transpose_cvt(const float* __restrict__ in, u16* __restrict__ out, int R, int C){
    __shared__ float t[32][33];
    int c0 = blockIdx.x*32, r0 = blockIdx.y*32;
    int tx = threadIdx.x, ty = threadIdx.y;
    #pragma unroll
    for (int i=0;i<4;++i) t[ty+i*8][tx] = in[(size_t)(r0+ty+i*8)*C + c0+tx];
    __syncthreads();
    #pragma unroll
    for (int i=0;i<4;++i) out[(size_t)(c0+ty+i*8)*R + r0+tx] = f2b(t[tx][ty+i*8]);
}

__global__ void transpose_cvt_z(const float* __restrict__ in, u16* __restrict__ out, int R, int C,
                                size_t inzs, size_t outzs){
    in += (size_t)blockIdx.z * inzs;
    out += (size_t)blockIdx.z * outzs;
    __shared__ float t[32][33];
    int c0 = blockIdx.x*32, r0 = blockIdx.y*32;
    int tx = threadIdx.x, ty = threadIdx.y;
    #pragma unroll
    for (int i=0;i<4;++i) t[ty+i*8][tx] = in[(size_t)(r0+ty+i*8)*C + c0+tx];
    __syncthreads();
    #pragma unroll
    for (int i=0;i<4;++i) out[(size_t)(c0+ty+i*8)*R + r0+tx] = f2b(t[tx][ty+i*8]);
}

__global__ void transpose_split(const float* __restrict__ in, u16* __restrict__ oh,
                                u16* __restrict__ ol, int R, int C){
    __shared__ float t[32][33];
    int c0 = blockIdx.x*32, r0 = blockIdx.y*32;
    int tx = threadIdx.x, ty = threadIdx.y;
    #pragma unroll
    for (int i=0;i<4;++i) t[ty+i*8][tx] = in[(size_t)(r0+ty+i*8)*C + c0+tx];
    __syncthreads();
    #pragma unroll
    for (int i=0;i<4;++i){
        float v = t[tx][ty+i*8];
        size_t idx = (size_t)(c0+ty+i*8)*R + r0+tx;
        u16 h = f2b(v);
        oh[idx] = h;
        ol[idx] = f2b(v - b2f(h));
    }
}

__global__ void transpose_split_z(const float* __restrict__ in, u16* __restrict__ oh,
                                  u16* __restrict__ ol, int R, int C,
                                  size_t inzs, size_t outzs){
    in += (size_t)blockIdx.z * inzs;
    oh += (size_t)blockIdx.z * outzs;
    ol += (size_t)blockIdx.z * outzs;
    __shared__ float t[32][33];
    int c0 = blockIdx.x*32, r0 = blockIdx.y*32;
    int tx = threadIdx.x, ty = threadIdx.y;
    #pragma unroll
    for (int i=0;i<4;++i) t[ty+i*8][tx] = in[(size_t)(r0+ty+i*8)*C + c0+tx];
    __syncthreads();
    #pragma unroll
    for (int i=0;i<4;++i){
        float v = t[tx][ty+i*8];
        size_t idx = (size_t)(c0+ty+i*8)*R + r0+tx;
        u16 h = f2b(v);
        oh[idx] = h;
        ol[idx] = f2b(v - b2f(h));
    }
}

__global__ __launch_bounds__(256) void combine_kernel(
    float* __restrict__ hf, const float* __restrict__ Mo,
    const int* __restrict__ slA, const int* __restrict__ slB,
    const int* __restrict__ e0, const int* __restrict__ e1,
    const float* __restrict__ w0, const float* __restrict__ w1,
    const float* __restrict__ b2l, u16* __restrict__ xbout){
    int t = blockIdx.x;
    int n = threadIdx.x*4;
    int sA = slA[t], sB = slB[t];
    const float* bA = b2l + e0[t]*1024;
    const float* bB = b2l + e1[t]*1024;
    float ww0 = w0[t], ww1 = w1[t];
    const float* pA = Mo + (size_t)sA*1024 + n;
    const float* pB = Mo + (size_t)sB*1024 + n;
    float* yp = hf + (size_t)t*1024 + n;
    u16* xp = xbout ? (xbout + (size_t)t*1024 + n) : nullptr;
    #pragma unroll
    for (int k=0;k<4;++k){
        float v = yp[k] + (pA[k] + bA[n+k])*ww0 + (pB[k] + bB[n+k])*ww1;
        yp[k] = v;
        if (xbout) xp[k] = f2b(v);
    }
}

__global__ __launch_bounds__(256) void qknorm_out(
    const float* __restrict__ qkvf, const float* __restrict__ qs, const float* __restrict__ ks,
    u16* __restrict__ qh, u16* __restrict__ ql, u16* __restrict__ kh, u16* __restrict__ kl,
    int split){
    int t = blockIdx.x*4 + (threadIdx.x>>6);
    int lane = threadIdx.x & 63;
    int h = lane>>2, d0 = (lane&3)*16;
    int b = t>>11, s = t & 2047;
    const float* qp = qkvf + (size_t)t*3072 + h*64 + d0;
    const float* kp = qp + 1024;
    float qv[16], kv[16];
    float sq = 0.f, sk = 0.f;
    #pragma unroll
    for (int i=0;i<16;++i){
        qv[i] = qp[i]; kv[i] = kp[i];
        sq += qv[i]*qv[i];  sk += kv[i]*kv[i];
    }
    sq += __shfl_xor(sq,1); sq += __shfl_xor(sq,2);
    sk += __shfl_xor(sk,1); sk += __shfl_xor(sk,2);
    float rq = rsqrtf(sq + 1e-6f) * 10.f;
    float rk = rsqrtf(sk + 1e-6f);
    size_t ob = ((size_t)(b*16+h)*2048 + s)*64 + d0;
    #pragma unroll
    for (int i=0;i<16;++i){
        float qn = qv[i]*rq*qs[d0+i];
        float kn = kv[i]*rk*ks[d0+i];
        u16 hq = f2b(qn), hk = f2b(kn);
        qh[ob+i] = hq; kh[ob+i] = hk;
        if (split){
            ql[ob+i] = f2b(qn - b2f(hq));
            kl[ob+i] = f2b(kn - b2f(hk));
        }
    }
}

__global__ void transpose_v(const float* __restrict__ qkvf, u16* __restrict__ vh,
                            u16* __restrict__ vl, int split){
    __shared__ float t[32][33];
    int s0 = blockIdx.x*32, d0 = blockIdx.y*32;
    int bh = blockIdx.z, b = bh>>4, h = bh&15;
    int tx = threadIdx.x, ty = threadIdx.y;
    #pragma unroll
    for (int i=0;i<4;++i)
        t[ty+i*8][tx] = qkvf[(size_t)(b*2048 + s0+ty+i*8)*3072 + 2048 + h*64 + d0 + tx];
    __syncthreads();
    #pragma unroll
    for (int i=0;i<4;++i){
        float v = t[tx][ty+i*8];
        size_t idx = ((size_t)bh*64 + d0+ty+i*8)*2048 + s0 + tx;
        u16 hv = f2b(v);
        vh[idx] = hv;
        if (split) vl[idx] = f2b(v - b2f(hv));
    }
}

// ---------------- MFMA flash attention (causal); bf16 hi(/lo) out ----------------
template<int SPLIT>
__global__ __launch_bounds__(256) void attn_flash(
    const u16* __restrict__ qh, const u16* __restrict__ ql,
    const u16* __restrict__ kh, const u16* __restrict__ kl,
    const u16* __restrict__ vth, const u16* __restrict__ vtl,
    u16* __restrict__ oh, u16* __restrict__ ol){
    int qt = blockIdx.x, bh = blockIdx.y;
    int tid = threadIdx.x, w = tid>>6, lane = tid & 63;
    int rr = lane & 15, hi = lane >> 4;
    __shared__ u16 Ksh[64*64];
    __shared__ u16 Vsh[64*64];
    __shared__ u16 Ksl[SPLIT ? 64*64 : 8];
    __shared__ u16 Vsl[SPLIT ? 64*64 : 8];
    __shared__ u16 Ps [4][16*72];
    __shared__ u16 Psl[SPLIT ? 4 : 1][16*72];
    int sw_w = ((tid>>3)&7)*8;
    int sw_r = (rr&7)*8;

    bf16x8 qfh[2], qfl[2];
    {
        size_t qo = (((size_t)bh*2048) + qt*64 + w*16 + rr)*64 + hi*8;
        qfh[0] = *(const bf16x8*)(qh + qo);
        qfh[1] = *(const bf16x8*)(qh + qo + 32);
        if (SPLIT){
            qfl[0] = *(const bf16x8*)(ql + qo);
            qfl[1] = *(const bf16x8*)(ql + qo + 32);
        }
    }
    f32x4 oacc[4];
    #pragma unroll
    for (int dt=0;dt<4;++dt) oacc[dt] = (f32x4){0.f,0.f,0.f,0.f};
    float mrow[4] = {-3e38f,-3e38f,-3e38f,-3e38f};
    float lrow[4] = {0.f,0.f,0.f,0.f};

    for (int kt=0; kt<=qt; ++kt){
        #pragma unroll
        for (int p=0;p<2;++p){
            int el = tid*8 + p*2048;
            int r = el>>6, c = el&63;
            int csw = c ^ sw_w;
            size_t koff = (((size_t)bh*2048) + kt*64 + r)*64 + c;
            size_t voff = ((size_t)bh*64 + r)*2048 + kt*64 + c;
            *(bf16x8*)&Ksh[r*64 + csw] = *(const bf16x8*)(kh + koff);
            *(bf16x8*)&Vsh[r*64 + csw] = *(const bf16x8*)(vth + voff);
            if (SPLIT){
                *(bf16x8*)&Ksl[r*64 + csw] = *(const bf16x8*)(kl + koff);
                *(bf16x8*)&Vsl[r*64 + csw] = *(const bf16x8*)(vtl + voff);
            }
        }
        __syncthreads();
        f32x4 sacc[4];
        #pragma unroll
        for (int nt=0;nt<4;++nt) sacc[nt] = (f32x4){0.f,0.f,0.f,0.f};
        #pragma unroll
        for (int kc=0;kc<2;++kc){
            int kk = (kc*32 + hi*8) ^ sw_r;
            #pragma unroll
            for (int nt=0;nt<4;++nt){
                bf16x8 kf = *(const bf16x8*)&Ksh[(nt*16+rr)*64 + kk];
                sacc[nt] = __builtin_amdgcn_mfma_f32_16x16x32_bf16(qfh[kc], kf, sacc[nt], 0,0,0);
                if (SPLIT){
                    bf16x8 kf2 = *(const bf16x8*)&Ksl[(nt*16+rr)*64 + kk];
                    sacc[nt] = __builtin_amdgcn_mfma_f32_16x16x32_bf16(qfh[kc], kf2, sacc[nt], 0,0,0);
                    sacc[nt] = __builtin_amdgcn_mfma_f32_16x16x32_bf16(qfl[kc], kf,  sacc[nt], 0,0,0);
                }
            }
        }
        if (kt == qt){
            #pragma unroll
            for (int nt=0;nt<4;++nt)
                #pragma unroll
                for (int j=0;j<4;++j)
                    if (nt*16 + rr > w*16 + hi*4 + j) sacc[nt][j] = -3e38f;
        }
        float corr[4];
        #pragma unroll
        for (int j=0;j<4;++j){
            float t = fmaxf(fmaxf(sacc[0][j],sacc[1][j]), fmaxf(sacc[2][j],sacc[3][j]));
            t = fmaxf(t, __shfl_xor(t,1));
            t = fmaxf(t, __shfl_xor(t,2));
            t = fmaxf(t, __shfl_xor(t,4));
            t = fmaxf(t, __shfl_xor(t,8));
            float mn = fmaxf(mrow[j], t);
            corr[j] = __expf(mrow[j] - mn);
            mrow[j] = mn;
        }
        float rsum[4] = {0.f,0.f,0.f,0.f};
        #pragma unroll
        for (int nt=0;nt<4;++nt)
            #pragma unroll
            for (int j=0;j<4;++j){
                float p = __expf(sacc[nt][j] - mrow[j]);
                sacc[nt][j] = p;
                rsum[j] += p;
            }
        #pragma unroll
        for (int j=0;j<4;++j){
            rsum[j] += __shfl_xor(rsum[j],1);
            rsum[j] += __shfl_xor(rsum[j],2);
            rsum[j] += __shfl_xor(rsum[j],4);
            rsum[j] += __shfl_xor(rsum[j],8);
            lrow[j] = lrow[j]*corr[j] + rsum[j];
        }
        #pragma unroll
        for (int dt=0;dt<4;++dt)
            #pragma unroll
            for (int j=0;j<4;++j) oacc[dt][j] *= corr[j];
        u16* pw = Ps[w];
        #pragma unroll
        for (int nt=0;nt<4;++nt)
            #pragma unroll
            for (int j=0;j<4;++j){
                float p = sacc[nt][j];
                u16 ph = f2b(p);
                pw[(hi*4+j)*72 + nt*16 + rr] = ph;
                if (SPLIT) Psl[w][(hi*4+j)*72 + nt*16 + rr] = f2b(p - b2f(ph));
            }
        __syncthreads();
        #pragma unroll
        for (int kc=0;kc<2;++kc){
            bf16x8 pf = *(const bf16x8*)&pw[rr*72 + kc*32 + hi*8];
            bf16x8 pfl;
            if (SPLIT) pfl = *(const bf16x8*)&Psl[w][rr*72 + kc*32 + hi*8];
            int vk = (kc*32 + hi*8) ^ sw_r;
            #pragma unroll
            for (int dt=0;dt<4;++dt){
                bf16x8 vf = *(const bf16x8*)&Vsh[(dt*16+rr)*64 + vk];
                oacc[dt] = __builtin_amdgcn_mfma_f32_16x16x32_bf16(pf, vf, oacc[dt], 0,0,0);
                if (SPLIT){
                    bf16x8 vf2 = *(const bf16x8*)&Vsl[(dt*16+rr)*64 + vk];
                    oacc[dt] = __builtin_amdgcn_mfma_f32_16x16x32_bf16(pf,  vf2, oacc[dt], 0,0,0);
                    oacc[dt] = __builtin_amdgcn_mfma_f32_16x16x32_bf16(pfl, vf,  oacc[dt], 0,0,0);
                }
            }
        }
        __syncthreads();
    }
    int b = bh>>4, h = bh&15;
    #pragma unroll
    for (int j=0;j<4;++j){
        float inv = 1.f/lrow[j];
        int srow = qt*64 + w*16 + hi*4 + j;
        size_t obase = ((size_t)b*2048 + srow)*1024 + h*64;
        #pragma unroll
        for (int dt=0;dt<4;++dt){
            float v = oacc[dt][j]*inv;
            u16 hh = f2b(v);
            oh[obase + dt*16 + rr] = hh;
            if (SPLIT) ol[obase + dt*16 + rr] = f2b(v - b2f(hh));
        }
    }
}

// ---------------- gating + routing (verified r17) ----------------
__global__ __launch_bounds__(256) void gating_top2(
    const float* __restrict__ h, const float* __restrict__ Wg,
    int* __restrict__ e0, int* __restrict__ e1,
    float* __restrict__ w0, float* __restrict__ w1){
    int t = blockIdx.x*4 + (threadIdx.x>>6);
    int lane = threadIdx.x & 63;
    const float* xr = h + (size_t)t*1024;
    float s[8] = {0,0,0,0,0,0,0,0};
    #pragma unroll
    for (int i=0;i<16;++i){
        int d = lane*16 + i;
        float xv = xr[d];
        const float* wr = Wg + d*8;
        #pragma unroll
        for (int ee=0;ee<8;++ee) s[ee] += xv * wr[ee];
    }
    #pragma unroll
    for (int off=1;off<64;off<<=1){
        #pragma unroll
        for (int ee=0;ee<8;++ee) s[ee] += __shfl_xor(s[ee], off);
    }
    if (lane == 0){
        int b0 = 0; float v0 = s[0];
        #pragma unroll
        for (int ee=1;ee<8;++ee) if (s[ee] > v0){ v0 = s[ee]; b0 = ee; }
        int b1i = -1; float v1 = -3e38f;
        #pragma unroll
        for (int ee=0;ee<8;++ee) if (ee != b0 && s[ee] > v1){ v1 = s[ee]; b1i = ee; }
        float z = __expf(v1 - v0);
        float inv = 1.f/(1.f + z);
        e0[t] = b0; e1[t] = b1i; w0[t] = inv; w1[t] = z*inv;
    }
}

__global__ __launch_bounds__(512) void routing_kernel(
    const int* __restrict__ e0, const int* __restrict__ e1,
    int* __restrict__ tok, int* __restrict__ slotA, int* __restrict__ slotB,
    int* __restrict__ counts, int* __restrict__ offs){
    int w = threadIdx.x>>6, lane = threadIdx.x & 63;
    __shared__ int soff[8];
    unsigned long long below = (1ull << lane) - 1ull;
    int c = 0;
    for (int base=0; base<4096; base+=64){
        int t = base + lane;
        bool f = (e0[t]==w) | (e1[t]==w);
        c += __popcll(__ballot(f));
    }
    if (lane == 0) soff[w] = c;
    __syncthreads();
    if (threadIdx.x == 0){
        int r = 0;
        for (int i=0;i<8;++i){ int ci = soff[i]; counts[i] = ci; offs[i] = r; soff[i] = r; r += ci; }
    }
    __syncthreads();
    int run = soff[w];
    for (int base=0; base<4096; base+=64){
        int t = base + lane;
        bool f0 = (e0[t]==w), f1 = (e1[t]==w);
        bool f = f0 | f1;
        unsigned long long m = __ballot(f);
        int pos = __popcll(m & below);
        if (f){
            int sl = run + pos;
            tok[sl] = t;
            if (f0) slotA[t] = sl; else slotB[t] = sl;
        }
        run += __popcll(m);
    }
}

// ---------------- launcher ----------------
extern "C" void kernel_launch(void* const* d_in, const int* in_sizes, int n_in,
                              void* d_out, int out_size, void* d_ws, size_t ws_size,
                              hipStream_t stream){
    const float* x  = (const float*)d_in[0];
    const float* Wq = (const float*)d_in[1];
    const float* Wk = (const float*)d_in[2];
    const float* Wv = (const float*)d_in[3];
    const float* Wo = (const float*)d_in[4];
    const float* qs = (const float*)d_in[5];
    const float* ks = (const float*)d_in[6];
    const float* Wg = (const float*)d_in[7];
    const float* W1 = (const float*)d_in[8];
    const float* b1 = (const float*)d_in[9];
    const float* W2 = (const float*)d_in[10];
    const float* b2 = (const float*)d_in[11];

    char* base = (char*)d_ws;
    const size_t MB = 1024*1024;

    float* qkvf = (float*)base;                // 0-48  (attn phase)
    float* Mo   = (float*)base;                // MoE: 0-32
    u16*   afhi = (u16*)  (base + 48*MB);      // 48-56  attn out hi (bf16)
    u16*   aflo = (u16*)  (base + 56*MB);      // 56-64  attn out lo
    u16*   qhbh = (u16*)  (base + 64*MB);
    u16*   khbh = (u16*)  (base + 72*MB);
    u16*   vtbh = (u16*)  (base + 80*MB);
    u16*   qhbl = (u16*)  (base + 88*MB);
    u16*   khbl = (u16*)  (base + 96*MB);
    u16*   vtbl = (u16*)  (base + 104*MB);
    u16*   xhi  = (u16*)  (base + 112*MB);
    u16*   xlo  = (u16*)  (base + 120*MB);
    u16*   xb   = (u16*)  (base + 128*MB);
    u16*   wTh  = (u16*)  (base + 136*MB);
    u16*   wTl  = (u16*)  (base + 144*MB);
    u16*   w2Th = (u16*)  (base + 152*MB);
    u16*   w2Tl = (u16*)  (base + 160*MB);
    // grouped MoE regions
    u16*   W1Th = (u16*)  (base + 32*MB);      // 32-96  (8 experts x 8MB)
    u16*   W1Tl = (u16*)  (base + 136*MB);     // 136-200
    u16*   W2Thb= (u16*)  (base + 200*MB);     // 200-264
    u16*   W2Tlb= (u16*)  (base + 264*MB);     // 264-328
    u16*   HeH  = (u16*)  (base + 328*MB);     // 328-392 [8192][4096]
    u16*   HeL  = (u16*)  (base + 392*MB);     // 392-456
    u16*   He16g= (u16*)  (base + 200*MB);     // L1 W2T
    // routing data
    char*  rbase = base + (size_t)458*MB;
    int*   e0b  = (int*)  rbase;
    int*   e1b  = e0b + 4096;
    float* w0b  = (float*)(e1b + 4096);
    float* w1b  = w0b + 4096;
    int*   tok  = (int*)(w1b + 4096);
    int*   slA  = tok + 8192;
    int*   slB  = slA + 4096;
    int*   cnts = slB + 4096;
    int*   offs = cnts + 8;

    float* hf = (float*)d_out;
    const size_t HTOK = (size_t)4096*1024;

    const size_t WSTRIDE = (size_t)1024*1024;
    const size_t ESTRIDE = (size_t)1024*4096;

    // =================== LAYER 0 (split-bf16: fp32-grade h1) ===================
    {
        init_split<<<16384,256,0,stream>>>(x, hf, xhi, xlo, (int)HTOK);
        gating_top2<<<1024,256,0,stream>>>(hf, Wg, e0b,e1b,w0b,w1b);
        routing_kernel<<<1,512,0,stream>>>(e0b,e1b, tok,slA,slB, cnts,offs);

        transpose_split<<<dim3(32,32),dim3(32,8),0,stream>>>(Wq, wTh,           wTl,           1024,1024);
        transpose_split<<<dim3(32,32),dim3(32,8),0,stream>>>(Wk, wTh + 1048576, wTl + 1048576, 1024,1024);
        transpose_split<<<dim3(32,32),dim3(32,8),0,stream>>>(Wv, wTh + 2097152, wTl + 2097152, 1024,1024);
        mgemm_s<0><<<dim3(24,32),256,0,stream>>>(xhi, xlo, wTh, wTl, qkvf, 4096,3072,1024,3072);

        qknorm_out<<<1024,256,0,stream>>>(qkvf, qs, ks, qhbh, qhbl, khbh, khbl, 1);
        transpose_v<<<dim3(64,2,32),dim3(32,8),0,stream>>>(qkvf, vtbh, vtbl, 1);
        attn_flash<1><<<dim3(32,32),256,0,stream>>>(qhbh, qhbl, khbh, khbl, vtbh, vtbl, afhi, aflo);

        transpose_split<<<dim3(32,32),dim3(32,8),0,stream>>>(Wo, w2Th, w2Tl, 1024,1024);
        mgemm_s<1><<<dim3(8,32),256,0,stream>>>(afhi, aflo, w2Th, w2Tl, hf, 4096,1024,1024,1024);

        transpose_split_z<<<dim3(128,32,8),dim3(32,8),0,stream>>>(W1, W1Th, W1Tl, 1024,4096, ESTRIDE, (size_t)4096*1024);
        transpose_split_z<<<dim3(32,128,8),dim3(32,8),0,stream>>>(W2, W2Thb, W2Tlb, 4096,1024, ESTRIDE, (size_t)1024*4096);
        mgemm_gs<true ><<<dim3(32,32,8),256,0,stream>>>(xhi, xlo, W1Th, W1Tl, nullptr, HeH, HeL, b1, tok,cnts,offs, 4096,1024);
        mgemm_gs<false><<<dim3(8,32,8),256,0,stream>>>(HeH, HeL, W2Thb, W2Tlb, Mo, nullptr,nullptr, nullptr, tok,cnts,offs, 1024,4096);

        combine_kernel<<<4096,256,0,stream>>>(hf, Mo, slA,slB, e0b,e1b, w0b,w1b, b2, xb);
    }

    // =================== LAYER 1 (plain bf16) ===================
    {
        gating_top2<<<1024,256,0,stream>>>(hf, Wg + (size_t)1024*8, e0b,e1b,w0b,w1b);
        routing_kernel<<<1,512,0,stream>>>(e0b,e1b, tok,slA,slB, cnts,offs);

        transpose_cvt<<<dim3(32,32),dim3(32,8),0,stream>>>(Wq + WSTRIDE, wTh,           1024,1024);
        transpose_cvt<<<dim3(32,32),dim3(32,8),0,stream>>>(Wk + WSTRIDE, wTh + 1048576, 1024,1024);
        transpose_cvt<<<dim3(32,32),dim3(32,8),0,stream>>>(Wv + WSTRIDE, wTh + 2097152, 1024,1024);
        mgemm<0><<<dim3(24,32),256,0,stream>>>(xb, wTh, qkvf, nullptr, nullptr,nullptr, 4096,3072,1024,3072);

        qknorm_out<<<1024,256,0,stream>>>(qkvf, qs + 64, ks + 64, qhbh, nullptr, khbh, nullptr, 0);
        transpose_v<<<dim3(64,2,32),dim3(32,8),0,stream>>>(qkvf, vtbh, nullptr, 0);
        attn_flash<0><<<dim3(32,32),256,0,stream>>>(qhbh, nullptr, khbh, nullptr, vtbh, nullptr, afhi, nullptr);

        transpose_cvt<<<dim3(32,32),dim3(32,8),0,stream>>>(Wo + WSTRIDE, w2Th, 1024,1024);
        mgemm<1><<<dim3(8,32),256,0,stream>>>(afhi, w2Th, hf, nullptr, nullptr,nullptr, 4096,1024,1024,1024);

        transpose_cvt_z<<<dim3(128,32,8),dim3(32,8),0,stream>>>(W1 + (size_t)8*ESTRIDE, W1Th, 1024,4096, ESTRIDE, (size_t)4096*1024);
        transpose_cvt_z<<<dim3(32,128,8),dim3(32,8),0,stream>>>(W2 + (size_t)8*ESTRIDE, He16g, 4096,1024, ESTRIDE, (size_t)1024*4096);
        mgemm_gp<true ><<<dim3(32,32,8),256,0,stream>>>(xb, W1Th, nullptr, (u16*)HeH, b1 + (size_t)8*4096, tok,cnts,offs, 4096,1024);
        mgemm_gp<false><<<dim3(8,32,8),256,0,stream>>>((u16*)HeH, He16g, Mo, nullptr, nullptr, tok,cnts,offs, 1024,4096);

        combine_kernel<<<4096,256,0,stream>>>(hf, Mo, slA,slB, e0b,e1b, w0b,w1b, b2 + (size_t)8*1024, nullptr);
    }
}

// Round 23
// 1933.289 us; speedup vs baseline: 1.7791x; 1.0013x over previous
//
#include <hip/hip_runtime.h>
#include <cstdint>

typedef unsigned short u16;
typedef __attribute__((ext_vector_type(4))) float f32x4;
typedef __attribute__((ext_vector_type(8))) __bf16 bf16x8;

#define DEV static __device__ __forceinline__

DEV u16 f2b(float f){
    unsigned int u = __builtin_bit_cast(unsigned int, f);
    u += 0x7fffu + ((u >> 16) & 1u);
    return (u16)(u >> 16);
}
DEV float b2f(u16 u){ return __builtin_bit_cast(float, (unsigned int)u << 16); }
DEV float gelu_f(float x){
    float x3 = x*x*x;
    return 0.5f*x*(1.f + tanhf(0.7978845608f*(x + 0.044715f*x3)));
}

DEV void gload16(const u16* g, u16* l){
    __builtin_amdgcn_global_load_lds(
        (const __attribute__((address_space(1))) unsigned int*)g,
        (__attribute__((address_space(3))) unsigned int*)l,
        16, 0, 0);
}

// ---------------- MFMA GEMM plain (verified) ----------------
template<int MODE>
__global__ __launch_bounds__(256) void mgemm(
    const u16* __restrict__ A, const u16* __restrict__ Bt,
    float* __restrict__ Cf, u16* __restrict__ Cb,
    const float* __restrict__ bias, const float* __restrict__ rowscale,
    int M, int N, int K, int ldc){
    int nb = blockIdx.x, mb = blockIdx.y;
    int tid = threadIdx.x, lane = tid & 63, w = tid >> 6;
    int rr = lane & 15, hi = lane >> 4;
    int wm = (w >> 1)*64, wn = (w & 1)*64;
    __shared__ u16 As[128*64];
    __shared__ u16 Bs[128*64];
    int sw_r = (rr & 7) * 8;
    int ce = (((lane&7) ^ (lane>>3)))*8;
    const u16* ap[4]; const u16* bp[4];
    u16* adst[4]; u16* bdst[4];
    #pragma unroll
    for (int p=0;p<4;++p){
        int r = (w*4+p)*8 + (lane>>3);
        ap[p] = A  + (size_t)(mb*128 + r)*K + ce;
        bp[p] = Bt + (size_t)(nb*128 + r)*K + ce;
        adst[p] = &As[(w*4+p)*512];
        bdst[p] = &Bs[(w*4+p)*512];
    }
    f32x4 acc[4][4];
    #pragma unroll
    for (int mt=0;mt<4;++mt)
        #pragma unroll
        for (int nt=0;nt<4;++nt) acc[mt][nt] = (f32x4){0.f,0.f,0.f,0.f};

    for (int k0=0; k0<K; k0+=64){
        #pragma unroll
        for (int p=0;p<4;++p){
            gload16(ap[p] + k0, adst[p]);
            gload16(bp[p] + k0, bdst[p]);
        }
        __syncthreads();
        #pragma unroll
        for (int kc=0;kc<2;++kc){
            int kk = (kc*32 + hi*8) ^ sw_r;
            bf16x8 af[4], bfv[4];
            #pragma unroll
            for (int mt=0;mt<4;++mt) af[mt]  = *(const bf16x8*)&As[(wm+mt*16+rr)*64 + kk];
            #pragma unroll
            for (int nt=0;nt<4;++nt) bfv[nt] = *(const bf16x8*)&Bs[(wn+nt*16+rr)*64 + kk];
            #pragma unroll
            for (int mt=0;mt<4;++mt)
                #pragma unroll
                for (int nt=0;nt<4;++nt)
                    acc[mt][nt] = __builtin_amdgcn_mfma_f32_16x16x32_bf16(af[mt], bfv[nt], acc[mt][nt], 0,0,0);
        }
        __syncthreads();
    }
    #pragma unroll
    for (int mt=0;mt<4;++mt){
        #pragma unroll
        for (int j=0;j<4;++j){
            int m = wm + mt*16 + hi*4 + j;
            size_t orow = (size_t)(mb*128 + m);
            #pragma unroll
            for (int nt=0;nt<4;++nt){
                int col = nb*128 + wn + nt*16 + rr;
                float v = acc[mt][nt][j];
                if (MODE == 0)      Cf[orow*ldc + col] = v;
                else if (MODE == 1) Cf[orow*ldc + col] += v;
            }
        }
    }
}

// ---------------- FUSED split-bf16 GEMM (dense, verified) ----------------
template<int MODE>
__global__ __launch_bounds__(256) void mgemm_s(
    const u16* __restrict__ Ah, const u16* __restrict__ Al,
    const u16* __restrict__ Bth, const u16* __restrict__ Btl,
    float* __restrict__ Cf, int M, int N, int K, int ldc){
    int nb = blockIdx.x, mb = blockIdx.y;
    int tid = threadIdx.x, lane = tid & 63, w = tid >> 6;
    int rr = lane & 15, hi = lane >> 4;
    int wm = (w >> 1)*64, wn = (w & 1)*64;
    __shared__ u16 Ash[128*64];
    __shared__ u16 Asl[128*64];
    __shared__ u16 Bsh[128*64];
    __shared__ u16 Bsl[128*64];
    int sw_r = (rr & 7) * 8;
    int ce = (((lane&7) ^ (lane>>3)))*8;
    const u16* ahp[4]; const u16* alp[4]; const u16* bhp[4]; const u16* blp[4];
    u16 *ahd[4], *ald[4], *bhd[4], *bld[4];
    #pragma unroll
    for (int p=0;p<4;++p){
        int r = (w*4+p)*8 + (lane>>3);
        size_t ao = (size_t)(mb*128 + r)*K + ce;
        size_t bo = (size_t)(nb*128 + r)*K + ce;
        ahp[p] = Ah + ao;  alp[p] = Al + ao;
        bhp[p] = Bth + bo; blp[p] = Btl + bo;
        ahd[p] = &Ash[(w*4+p)*512]; ald[p] = &Asl[(w*4+p)*512];
        bhd[p] = &Bsh[(w*4+p)*512]; bld[p] = &Bsl[(w*4+p)*512];
    }
    f32x4 acc[4][4];
    #pragma unroll
    for (int mt=0;mt<4;++mt)
        #pragma unroll
        for (int nt=0;nt<4;++nt) acc[mt][nt] = (f32x4){0.f,0.f,0.f,0.f};

    for (int k0=0; k0<K; k0+=64){
        #pragma unroll
        for (int p=0;p<4;++p){
            gload16(ahp[p] + k0, ahd[p]);
            gload16(alp[p] + k0, ald[p]);
            gload16(bhp[p] + k0, bhd[p]);
            gload16(blp[p] + k0, bld[p]);
        }
        __syncthreads();
        #pragma unroll
        for (int kc=0;kc<2;++kc){
            int kk = (kc*32 + hi*8) ^ sw_r;
            bf16x8 afh[4], afl[4], bfh[4], bfl[4];
            #pragma unroll
            for (int mt=0;mt<4;++mt){
                afh[mt] = *(const bf16x8*)&Ash[(wm+mt*16+rr)*64 + kk];
                afl[mt] = *(const bf16x8*)&Asl[(wm+mt*16+rr)*64 + kk];
            }
            #pragma unroll
            for (int nt=0;nt<4;++nt){
                bfh[nt] = *(const bf16x8*)&Bsh[(wn+nt*16+rr)*64 + kk];
                bfl[nt] = *(const bf16x8*)&Bsl[(wn+nt*16+rr)*64 + kk];
            }
            #pragma unroll
            for (int mt=0;mt<4;++mt)
                #pragma unroll
                for (int nt=0;nt<4;++nt){
                    acc[mt][nt] = __builtin_amdgcn_mfma_f32_16x16x32_bf16(afh[mt], bfh[nt], acc[mt][nt], 0,0,0);
                    acc[mt][nt] = __builtin_amdgcn_mfma_f32_16x16x32_bf16(afh[mt], bfl[nt], acc[mt][nt], 0,0,0);
                    acc[mt][nt] = __builtin_amdgcn_mfma_f32_16x16x32_bf16(afl[mt], bfh[nt], acc[mt][nt], 0,0,0);
                }
        }
        __syncthreads();
    }
    #pragma unroll
    for (int mt=0;mt<4;++mt){
        #pragma unroll
        for (int j=0;j<4;++j){
            int m = wm + mt*16 + hi*4 + j;
            size_t orow = (size_t)(mb*128 + m);
            #pragma unroll
            for (int nt=0;nt<4;++nt){
                int col = nb*128 + wn + nt*16 + rr;
                float v = acc[mt][nt][j];
                if (MODE == 0)      Cf[orow*ldc + col] = v;
                else if (MODE == 1) Cf[orow*ldc + col] += v;
            }
        }
    }
}

// ---------------- GROUPED split expert GEMM (r20 grid order: nb = blockIdx.x) ----------------
template<bool UP>
__global__ __launch_bounds__(256) void mgemm_gs(
    const u16* __restrict__ Ah, const u16* __restrict__ Al,
    const u16* __restrict__ Bth, const u16* __restrict__ Btl,
    float* __restrict__ Cf, u16* __restrict__ OutH, u16* __restrict__ OutL,
    const float* __restrict__ b1all,
    const int* __restrict__ tok, const int* __restrict__ counts, const int* __restrict__ offs,
    int N, int K){
    int e = blockIdx.z;
    int cnt = counts[e];
    int nb = blockIdx.x, mb = blockIdx.y;
    if (mb*128 >= cnt) return;
    int slot0 = offs[e];
    const u16* Bh = Bth + (size_t)e*N*K;
    const u16* Bl = Btl + (size_t)e*N*K;
    int tid = threadIdx.x, lane = tid & 63, w = tid >> 6;
    int rr = lane & 15, hi = lane >> 4;
    int wm = (w >> 1)*64, wn = (w & 1)*64;
    __shared__ u16 Ash[128*64];
    __shared__ u16 Asl[128*64];
    __shared__ u16 Bsh[128*64];
    __shared__ u16 Bsl[128*64];
    int sw_r = (rr & 7) * 8;
    int ce = (((lane&7) ^ (lane>>3)))*8;
    const u16* ahp[4]; const u16* alp[4]; const u16* bhp[4]; const u16* blp[4];
    u16 *ahd[4], *ald[4], *bhd[4], *bld[4];
    #pragma unroll
    for (int p=0;p<4;++p){
        int r = (w*4+p)*8 + (lane>>3);
        int lr = mb*128 + r;
        int lc = lr < cnt ? lr : (cnt-1);
        size_t arow = UP ? (size_t)tok[slot0 + lc] : (size_t)(slot0 + lc);
        ahp[p] = Ah + arow*K + ce;
        alp[p] = Al + arow*K + ce;
        bhp[p] = Bh + (size_t)(nb*128 + r)*K + ce;
        blp[p] = Bl + (size_t)(nb*128 + r)*K + ce;
        ahd[p] = &Ash[(w*4+p)*512]; ald[p] = &Asl[(w*4+p)*512];
        bhd[p] = &Bsh[(w*4+p)*512]; bld[p] = &Bsl[(w*4+p)*512];
    }
    f32x4 acc[4][4];
    #pragma unroll
    for (int mt=0;mt<4;++mt)
        #pragma unroll
        for (int nt=0;nt<4;++nt) acc[mt][nt] = (f32x4){0.f,0.f,0.f,0.f};

    for (int k0=0; k0<K; k0+=64){
        #pragma unroll
        for (int p=0;p<4;++p){
            gload16(ahp[p] + k0, ahd[p]);
            gload16(alp[p] + k0, ald[p]);
            gload16(bhp[p] + k0, bhd[p]);
            gload16(blp[p] + k0, bld[p]);
        }
        __syncthreads();
        #pragma unroll
        for (int kc=0;kc<2;++kc){
            int kk = (kc*32 + hi*8) ^ sw_r;
            bf16x8 afh[4], afl[4], bfh[4], bfl[4];
            #pragma unroll
            for (int mt=0;mt<4;++mt){
                afh[mt] = *(const bf16x8*)&Ash[(wm+mt*16+rr)*64 + kk];
                afl[mt] = *(const bf16x8*)&Asl[(wm+mt*16+rr)*64 + kk];
            }
            #pragma unroll
            for (int nt=0;nt<4;++nt){
                bfh[nt] = *(const bf16x8*)&Bsh[(wn+nt*16+rr)*64 + kk];
                bfl[nt] = *(const bf16x8*)&Bsl[(wn+nt*16+rr)*64 + kk];
            }
            #pragma unroll
            for (int mt=0;mt<4;++mt)
                #pragma unroll
                for (int nt=0;nt<4;++nt){
                    acc[mt][nt] = __builtin_amdgcn_mfma_f32_16x16x32_bf16(afh[mt], bfh[nt], acc[mt][nt], 0,0,0);
                    acc[mt][nt] = __builtin_amdgcn_mfma_f32_16x16x32_bf16(afh[mt], bfl[nt], acc[mt][nt], 0,0,0);
                    acc[mt][nt] = __builtin_amdgcn_mfma_f32_16x16x32_bf16(afl[mt], bfh[nt], acc[mt][nt], 0,0,0);
                }
        }
        __syncthreads();
    }
    const float* b1e = UP ? (b1all + (size_t)e*N) : nullptr;
    #pragma unroll
    for (int mt=0;mt<4;++mt){
        #pragma unroll
        for (int j=0;j<4;++j){
            int m = wm + mt*16 + hi*4 + j;
            int lr = mb*128 + m;
            if (lr >= cnt) continue;
            size_t orow = (size_t)(slot0 + lr);
            #pragma unroll
            for (int nt=0;nt<4;++nt){
                int col = nb*128 + wn + nt*16 + rr;
                float v = acc[mt][nt][j];
                if (UP){
                    float g = gelu_f(v + b1e[col]);
                    u16 h = f2b(g);
                    OutH[orow*N + col] = h;
                    OutL[orow*N + col] = f2b(g - b2f(h));
                } else {
                    Cf[orow*N + col] = v;
                }
            }
        }
    }
}

// ---------------- GROUPED plain expert GEMM (L1; r20 grid order) ----------------
template<bool UP>
__global__ __launch_bounds__(256) void mgemm_gp(
    const u16* __restrict__ A, const u16* __restrict__ Bt,
    float* __restrict__ Cf, u16* __restrict__ Cb, const float* __restrict__ b1all,
    const int* __restrict__ tok, const int* __restrict__ counts, const int* __restrict__ offs,
    int N, int K){
    int e = blockIdx.z;
    int cnt = counts[e];
    int nb = blockIdx.x, mb = blockIdx.y;
    if (mb*128 >= cnt) return;
    int slot0 = offs[e];
    const u16* Bte = Bt + (size_t)e*N*K;
    int tid = threadIdx.x, lane = tid & 63, w = tid >> 6;
    int rr = lane & 15, hi = lane >> 4;
    int wm = (w >> 1)*64, wn = (w & 1)*64;
    __shared__ u16 As[128*64];
    __shared__ u16 Bs[128*64];
    int sw_r = (rr & 7) * 8;
    int ce = (((lane&7) ^ (lane>>3)))*8;
    const u16* aptr[4]; const u16* bptr[4];
    u16 *adst[4], *bdst[4];
    #pragma unroll
    for (int p=0;p<4;++p){
        int r = (w*4+p)*8 + (lane>>3);
        int lr = mb*128 + r;
        int lc = lr < cnt ? lr : (cnt-1);
        size_t arow = UP ? (size_t)tok[slot0 + lc] : (size_t)(slot0 + lc);
        aptr[p] = A  + arow*K + ce;
        bptr[p] = Bte + (size_t)(nb*128 + r)*K + ce;
        adst[p] = &As[(w*4+p)*512];
        bdst[p] = &Bs[(w*4+p)*512];
    }
    f32x4 acc[4][4];
    #pragma unroll
    for (int mt=0;mt<4;++mt)
        #pragma unroll
        for (int nt=0;nt<4;++nt) acc[mt][nt] = (f32x4){0.f,0.f,0.f,0.f};

    for (int k0=0; k0<K; k0+=64){
        #pragma unroll
        for (int p=0;p<4;++p){
            gload16(aptr[p] + k0, adst[p]);
            gload16(bptr[p] + k0, bdst[p]);
        }
        __syncthreads();
        #pragma unroll
        for (int kc=0;kc<2;++kc){
            int kk = (kc*32 + hi*8) ^ sw_r;
            bf16x8 af[4], bfv[4];
            #pragma unroll
            for (int mt=0;mt<4;++mt) af[mt]  = *(const bf16x8*)&As[(wm+mt*16+rr)*64 + kk];
            #pragma unroll
            for (int nt=0;nt<4;++nt) bfv[nt] = *(const bf16x8*)&Bs[(wn+nt*16+rr)*64 + kk];
            #pragma unroll
            for (int mt=0;mt<4;++mt)
                #pragma unroll
                for (int nt=0;nt<4;++nt)
                    acc[mt][nt] = __builtin_amdgcn_mfma_f32_16x16x32_bf16(af[mt], bfv[nt], acc[mt][nt], 0,0,0);
        }
        __syncthreads();
    }
    const float* b1e = UP ? (b1all + (size_t)e*N) : nullptr;
    #pragma unroll
    for (int mt=0;mt<4;++mt){
        #pragma unroll
        for (int j=0;j<4;++j){
            int m = wm + mt*16 + hi*4 + j;
            int lr = mb*128 + m;
            if (lr >= cnt) continue;
            size_t orow = (size_t)(slot0 + lr);
            #pragma unroll
            for (int nt=0;nt<4;++nt){
                int col = nb*128 + wn + nt*16 + rr;
                float v = acc[mt][nt][j];
                if (UP) Cb[orow*N + col] = f2b(gelu_f(v + b1e[col]));
                else    Cf[orow*N + col] = v;
            }
        }
    }
}

// ---------------- elementwise / transpose helpers ----------------
__global__ __launch_bounds__(256) void init_split(const float* __restrict__ x,
                                                  float* __restrict__ hf,
                                                  u16* __restrict__ oh, u16* __restrict__ ol, int n){
    int i = blockIdx.x*256 + threadIdx.x;
    if (i < n){
        float v = x[i];
        hf[i] = v;
        u16 h = f2b(v);
        oh[i] = h;
        ol[i] = f2b(v - b2f(h));
    }
}

__global__ void transpose_cvt(const float* __restrict__ in, u16* __restrict__ out, int R, int C){
    __shared__ float t[32][33];
    int c0 = blockIdx.x*32, r0 = blockIdx.y*32;
    int tx = threadIdx.x, ty = threadIdx.y;
    #pragma unroll
    for (int i=0;i<4;++i) t[ty+i*8][tx] = in[(size_t)(r0+ty+i*8)*C + c0+tx];
    __syncthreads();
    #pragma unroll
    for (int i=0;i<4;++i) out[(size_t)(c0+ty+i*8)*R + r0+tx] = f2b(t[tx][ty+i*8]);
}

__global__ void transpose_cvt_z(const float* __restrict__ in, u16* __restrict__ out, int R, int C,
                                size_t inzs, size_t outzs){
    in += (size_t)blockIdx.z * inzs;
    out += (size_t)blockIdx.z * outzs;
    __shared__ float t[32][33];
    int c0 = blockIdx.x*32, r0 = blockIdx.y*32;
    int tx = threadIdx.x, ty = threadIdx.y;
    #pragma unroll
    for (int i=0;i<4;++i) t[ty+i*8][tx] = in[(size_t)(r0+ty+i*8)*C + c0+tx];
    __syncthreads();
    #pragma unroll
    for (int i=0;i<4;++i) out[(size_t)(c0+ty+i*8)*R + r0+tx] = f2b(t[tx][ty+i*8]);
}

__global__ void transpose_split(const float* __restrict__ in, u16* __restrict__ oh,
                                u16* __restrict__ ol, int R, int C){
    __shared__ float t[32][33];
    int c0 = blockIdx.x*32, r0 = blockIdx.y*32;
    int tx = threadIdx.x, ty = threadIdx.y;
    #pragma unroll
    for (int i=0;i<4;++i) t[ty+i*8][tx] = in[(size_t)(r0+ty+i*8)*C + c0+tx];
    __syncthreads();
    #pragma unroll
    for (int i=0;i<4;++i){
        float v = t[tx][ty+i*8];
        size_t idx = (size_t)(c0+ty+i*8)*R + r0+tx;
        u16 h = f2b(v);
        oh[idx] = h;
        ol[idx] = f2b(v - b2f(h));
    }
}

__global__ void transpose_split_z(const float* __restrict__ in, u16* __restrict__ oh,
                                  u16* __restrict__ ol, int R, int C,
                                  size_t inzs, size_t outzs){
    in += (size_t)blockIdx.z * inzs;
    oh += (size_t)blockIdx.z * outzs;
    ol += (size_t)blockIdx.z * outzs;
    __shared__ float t[32][33];
    int c0 = blockIdx.x*32, r0 = blockIdx.y*32;
    int tx = threadIdx.x, ty = threadIdx.y;
    #pragma unroll
    for (int i=0;i<4;++i) t[ty+i*8][tx] = in[(size_t)(r0+ty+i*8)*C + c0+tx];
    __syncthreads();
    #pragma unroll
    for (int i=0;i<4;++i){
        float v = t[tx][ty+i*8];
        size_t idx = (size_t)(c0+ty+i*8)*R + r0+tx;
        u16 h = f2b(v);
        oh[idx] = h;
        ol[idx] = f2b(v - b2f(h));
    }
}

__global__ __launch_bounds__(256) void combine_kernel(
    float* __restrict__ hf, const float* __restrict__ Mo,
    const int* __restrict__ slA, const int* __restrict__ slB,
    const int* __restrict__ e0, const int* __restrict__ e1,
    const float* __restrict__ w0, const float* __restrict__ w1,
    const float* __restrict__ b2l, u16* __restrict__ xbout){
    int t = blockIdx.x;
    int n = threadIdx.x*4;
    int sA = slA[t], sB = slB[t];
    const float* bA = b2l + e0[t]*1024;
    const float* bB = b2l + e1[t]*1024;
    float ww0 = w0[t], ww1 = w1[t];
    const float* pA = Mo + (size_t)sA*1024 + n;
    const float* pB = Mo + (size_t)sB*1024 + n;
    float* yp = hf + (size_t)t*1024 + n;
    u16* xp = xbout ? (xbout + (size_t)t*1024 + n) : nullptr;
    #pragma unroll
    for (int k=0;k<4;++k){
        float v = yp[k] + (pA[k] + bA[n+k])*ww0 + (pB[k] + bB[n+k])*ww1;
        yp[k] = v;
        if (xbout) xp[k] = f2b(v);
    }
}

__global__ __launch_bounds__(256) void qknorm_out(
    const float* __restrict__ qkvf, const float* __restrict__ qs, const float* __restrict__ ks,
    u16* __restrict__ qh, u16* __restrict__ ql, u16* __restrict__ kh, u16* __restrict__ kl,
    int split){
    int t = blockIdx.x*4 + (threadIdx.x>>6);
    int lane = threadIdx.x & 63;
    int h = lane>>2, d0 = (lane&3)*16;
    int b = t>>11, s = t & 2047;
    const float* qp = qkvf + (size_t)t*3072 + h*64 + d0;
    const float* kp = qp + 1024;
    float qv[16], kv[16];
    float sq = 0.f, sk = 0.f;
    #pragma unroll
    for (int i=0;i<16;++i){
        qv[i] = qp[i]; kv[i] = kp[i];
        sq += qv[i]*qv[i];  sk += kv[i]*kv[i];
    }
    sq += __shfl_xor(sq,1); sq += __shfl_xor(sq,2);
    sk += __shfl_xor(sk,1); sk += __shfl_xor(sk,2);
    float rq = rsqrtf(sq + 1e-6f) * 10.f;
    float rk = rsqrtf(sk + 1e-6f);
    size_t ob = ((size_t)(b*16+h)*2048 + s)*64 + d0;
    #pragma unroll
    for (int i=0;i<16;++i){
        float qn = qv[i]*rq*qs[d0+i];
        float kn = kv[i]*rk*ks[d0+i];
        u16 hq = f2b(qn), hk = f2b(kn);
        qh[ob+i] = hq; kh[ob+i] = hk;
        if (split){
            ql[ob+i] = f2b(qn - b2f(hq));
            kl[ob+i] = f2b(kn - b2f(hk));
        }
    }
}

__global__ void transpose_v(const float* __restrict__ qkvf, u16* __restrict__ vh,
                            u16* __restrict__ vl, int split){
    __shared__ float t[32][33];
    int s0 = blockIdx.x*32, d0 = blockIdx.y*32;
    int bh = blockIdx.z, b = bh>>4, h = bh&15;
    int tx = threadIdx.x, ty = threadIdx.y;
    #pragma unroll
    for (int i=0;i<4;++i)
        t[ty+i*8][tx] = qkvf[(size_t)(b*2048 + s0+ty+i*8)*3072 + 2048 + h*64 + d0 + tx];
    __syncthreads();
    #pragma unroll
    for (int i=0;i<4;++i){
        float v = t[tx][ty+i*8];
        size_t idx = ((size_t)bh*64 + d0+ty+i*8)*2048 + s0 + tx;
        u16 hv = f2b(v);
        vh[idx] = hv;
        if (split) vl[idx] = f2b(v - b2f(hv));
    }
}

// ---------------- MFMA flash attention (causal); tail-first qt order ----------------
template<int SPLIT>
__global__ __launch_bounds__(256) void attn_flash(
    const u16* __restrict__ qh, const u16* __restrict__ ql,
    const u16* __restrict__ kh, const u16* __restrict__ kl,
    const u16* __restrict__ vth, const u16* __restrict__ vtl,
    u16* __restrict__ oh, u16* __restrict__ ol){
    // tail-first: heaviest q-tiles (most KV iterations) dispatch first (LPT scheduling)
    int qt = (int)gridDim.x - 1 - (int)blockIdx.x;
    int bh = blockIdx.y;
    int tid = threadIdx.x, w = tid>>6, lane = tid & 63;
    int rr = lane & 15, hi = lane >> 4;
    __shared__ u16 Ksh[64*64];
    __shared__ u16 Vsh[64*64];
    __shared__ u16 Ksl[SPLIT ? 64*64 : 8];
    __shared__ u16 Vsl[SPLIT ? 64*64 : 8];
    __shared__ u16 Ps [4][16*72];
    __shared__ u16 Psl[SPLIT ? 4 : 1][16*72];
    int sw_w = ((tid>>3)&7)*8;
    int sw_r = (rr&7)*8;

    bf16x8 qfh[2], qfl[2];
    {
        size_t qo = (((size_t)bh*2048) + qt*64 + w*16 + rr)*64 + hi*8;
        qfh[0] = *(const bf16x8*)(qh + qo);
        qfh[1] = *(const bf16x8*)(qh + qo + 32);
        if (SPLIT){
            qfl[0] = *(const bf16x8*)(ql + qo);
            qfl[1] = *(const bf16x8*)(ql + qo + 32);
        }
    }
    f32x4 oacc[4];
    #pragma unroll
    for (int dt=0;dt<4;++dt) oacc[dt] = (f32x4){0.f,0.f,0.f,0.f};
    float mrow[4] = {-3e38f,-3e38f,-3e38f,-3e38f};
    float lrow[4] = {0.f,0.f,0.f,0.f};

    for (int kt=0; kt<=qt; ++kt){
        #pragma unroll
        for (int p=0;p<2;++p){
            int el = tid*8 + p*2048;
            int r = el>>6, c = el&63;
            int csw = c ^ sw_w;
            size_t koff = (((size_t)bh*2048) + kt*64 + r)*64 + c;
            size_t voff = ((size_t)bh*64 + r)*2048 + kt*64 + c;
            *(bf16x8*)&Ksh[r*64 + csw] = *(const bf16x8*)(kh + koff);
            *(bf16x8*)&Vsh[r*64 + csw] = *(const bf16x8*)(vth + voff);
            if (SPLIT){
                *(bf16x8*)&Ksl[r*64 + csw] = *(const bf16x8*)(kl + koff);
                *(bf16x8*)&Vsl[r*64 + csw] = *(const bf16x8*)(vtl + voff);
            }
        }
        __syncthreads();
        f32x4 sacc[4];
        #pragma unroll
        for (int nt=0;nt<4;++nt) sacc[nt] = (f32x4){0.f,0.f,0.f,0.f};
        #pragma unroll
        for (int kc=0;kc<2;++kc){
            int kk = (kc*32 + hi*8) ^ sw_r;
            #pragma unroll
            for (int nt=0;nt<4;++nt){
                bf16x8 kf = *(const bf16x8*)&Ksh[(nt*16+rr)*64 + kk];
                sacc[nt] = __builtin_amdgcn_mfma_f32_16x16x32_bf16(qfh[kc], kf, sacc[nt], 0,0,0);
                if (SPLIT){
                    bf16x8 kf2 = *(const bf16x8*)&Ksl[(nt*16+rr)*64 + kk];
                    sacc[nt] = __builtin_amdgcn_mfma_f32_16x16x32_bf16(qfh[kc], kf2, sacc[nt], 0,0,0);
                    sacc[nt] = __builtin_amdgcn_mfma_f32_16x16x32_bf16(qfl[kc], kf,  sacc[nt], 0,0,0);
                }
            }
        }
        if (kt == qt){
            #pragma unroll
            for (int nt=0;nt<4;++nt)
                #pragma unroll
                for (int j=0;j<4;++j)
                    if (nt*16 + rr > w*16 + hi*4 + j) sacc[nt][j] = -3e38f;
        }
        float corr[4];
        #pragma unroll
        for (int j=0;j<4;++j){
            float t = fmaxf(fmaxf(sacc[0][j],sacc[1][j]), fmaxf(sacc[2][j],sacc[3][j]));
            t = fmaxf(t, __shfl_xor(t,1));
            t = fmaxf(t, __shfl_xor(t,2));
            t = fmaxf(t, __shfl_xor(t,4));
            t = fmaxf(t, __shfl_xor(t,8));
            float mn = fmaxf(mrow[j], t);
            corr[j] = __expf(mrow[j] - mn);
            mrow[j] = mn;
        }
        float rsum[4] = {0.f,0.f,0.f,0.f};
        #pragma unroll
        for (int nt=0;nt<4;++nt)
            #pragma unroll
            for (int j=0;j<4;++j){
                float p = __expf(sacc[nt][j] - mrow[j]);
                sacc[nt][j] = p;
                rsum[j] += p;
            }
        #pragma unroll
        for (int j=0;j<4;++j){
            rsum[j] += __shfl_xor(rsum[j],1);
            rsum[j] += __shfl_xor(rsum[j],2);
            rsum[j] += __shfl_xor(rsum[j],4);
            rsum[j] += __shfl_xor(rsum[j],8);
            lrow[j] = lrow[j]*corr[j] + rsum[j];
        }
        #pragma unroll
        for (int dt=0;dt<4;++dt)
            #pragma unroll
            for (int j=0;j<4;++j) oacc[dt][j] *= corr[j];
        u16* pw = Ps[w];
        #pragma unroll
        for (int nt=0;nt<4;++nt)
            #pragma unroll
            for (int j=0;j<4;++j){
                float p = sacc[nt][j];
                u16 ph = f2b(p);
                pw[(hi*4+j)*72 + nt*16 + rr] = ph;
                if (SPLIT) Psl[w][(hi*4+j)*72 + nt*16 + rr] = f2b(p - b2f(ph));
            }
        __syncthreads();
        #pragma unroll
        for (int kc=0;kc<2;++kc){
            bf16x8 pf = *(const bf16x8*)&pw[rr*72 + kc*32 + hi*8];
            bf16x8 pfl;
            if (SPLIT) pfl = *(const bf16x8*)&Psl[w][rr*72 + kc*32 + hi*8];
            int vk = (kc*32 + hi*8) ^ sw_r;
            #pragma unroll
            for (int dt=0;dt<4;++dt){
                bf16x8 vf = *(const bf16x8*)&Vsh[(dt*16+rr)*64 + vk];
                oacc[dt] = __builtin_amdgcn_mfma_f32_16x16x32_bf16(pf, vf, oacc[dt], 0,0,0);
                if (SPLIT){
                    bf16x8 vf2 = *(const bf16x8*)&Vsl[(dt*16+rr)*64 + vk];
                    oacc[dt] = __builtin_amdgcn_mfma_f32_16x16x32_bf16(pf,  vf2, oacc[dt], 0,0,0);
                    oacc[dt] = __builtin_amdgcn_mfma_f32_16x16x32_bf16(pfl, vf,  oacc[dt], 0,0,0);
                }
            }
        }
        __syncthreads();
    }
    int b = bh>>4, h = bh&15;
    #pragma unroll
    for (int j=0;j<4;++j){
        float inv = 1.f/lrow[j];
        int srow = qt*64 + w*16 + hi*4 + j;
        size_t obase = ((size_t)b*2048 + srow)*1024 + h*64;
        #pragma unroll
        for (int dt=0;dt<4;++dt){
            float v = oacc[dt][j]*inv;
            u16 hh = f2b(v);
            oh[obase + dt*16 + rr] = hh;
            if (SPLIT) ol[obase + dt*16 + rr] = f2b(v - b2f(hh));
        }
    }
}

// ---------------- gating + routing (verified r17) ----------------
__global__ __launch_bounds__(256) void gating_top2(
    const float* __restrict__ h, const float* __restrict__ Wg,
    int* __restrict__ e0, int* __restrict__ e1,
    float* __restrict__ w0, float* __restrict__ w1){
    int t = blockIdx.x*4 + (threadIdx.x>>6);
    int lane = threadIdx.x & 63;
    const float* xr = h + (size_t)t*1024;
    float s[8] = {0,0,0,0,0,0,0,0};
    #pragma unroll
    for (int i=0;i<16;++i){
        int d = lane*16 + i;
        float xv = xr[d];
        const float* wr = Wg + d*8;
        #pragma unroll
        for (int ee=0;ee<8;++ee) s[ee] += xv * wr[ee];
    }
    #pragma unroll
    for (int off=1;off<64;off<<=1){
        #pragma unroll
        for (int ee=0;ee<8;++ee) s[ee] += __shfl_xor(s[ee], off);
    }
    if (lane == 0){
        int b0 = 0; float v0 = s[0];
        #pragma unroll
        for (int ee=1;ee<8;++ee) if (s[ee] > v0){ v0 = s[ee]; b0 = ee; }
        int b1i = -1; float v1 = -3e38f;
        #pragma unroll
        for (int ee=0;ee<8;++ee) if (ee != b0 && s[ee] > v1){ v1 = s[ee]; b1i = ee; }
        float z = __expf(v1 - v0);
        float inv = 1.f/(1.f + z);
        e0[t] = b0; e1[t] = b1i; w0[t] = inv; w1[t] = z*inv;
    }
}

__global__ __launch_bounds__(512) void routing_kernel(
    const int* __restrict__ e0, const int* __restrict__ e1,
    int* __restrict__ tok, int* __restrict__ slotA, int* __restrict__ slotB,
    int* __restrict__ counts, int* __restrict__ offs){
    int w = threadIdx.x>>6, lane = threadIdx.x & 63;
    __shared__ int soff[8];
    unsigned long long below = (1ull << lane) - 1ull;
    int c = 0;
    for (int base=0; base<4096; base+=64){
        int t = base + lane;
        bool f = (e0[t]==w) | (e1[t]==w);
        c += __popcll(__ballot(f));
    }
    if (lane == 0) soff[w] = c;
    __syncthreads();
    if (threadIdx.x == 0){
        int r = 0;
        for (int i=0;i<8;++i){ int ci = soff[i]; counts[i] = ci; offs[i] = r; soff[i] = r; r += ci; }
    }
    __syncthreads();
    int run = soff[w];
    for (int base=0; base<4096; base+=64){
        int t = base + lane;
        bool f0 = (e0[t]==w), f1 = (e1[t]==w);
        bool f = f0 | f1;
        unsigned long long m = __ballot(f);
        int pos = __popcll(m & below);
        if (f){
            int sl = run + pos;
            tok[sl] = t;
            if (f0) slotA[t] = sl; else slotB[t] = sl;
        }
        run += __popcll(m);
    }
}

// ---------------- launcher ----------------
extern "C" void kernel_launch(void* const* d_in, const int* in_sizes, int n_in,
                              void* d_out, int out_size, void* d_ws, size_t ws_size,
                              hipStream_t stream){
    const float* x  = (const float*)d_in[0];
    const float* Wq = (const float*)d_in[1];
    const float* Wk = (const float*)d_in[2];
    const float* Wv = (const float*)d_in[3];
    const float* Wo = (const float*)d_in[4];
    const float* qs = (const float*)d_in[5];
    const float* ks = (const float*)d_in[6];
    const float* Wg = (const float*)d_in[7];
    const float* W1 = (const float*)d_in[8];
    const float* b1 = (const float*)d_in[9];
    const float* W2 = (const float*)d_in[10];
    const float* b2 = (const float*)d_in[11];

    char* base = (char*)d_ws;
    const size_t MB = 1024*1024;

    float* qkvf = (float*)base;                // 0-48  (attn phase)
    float* Mo   = (float*)base;                // MoE: 0-32
    u16*   afhi = (u16*)  (base + 48*MB);      // 48-56  attn out hi (bf16)
    u16*   aflo = (u16*)  (base + 56*MB);      // 56-64  attn out lo
    u16*   qhbh = (u16*)  (base + 64*MB);
    u16*   khbh = (u16*)  (base + 72*MB);
    u16*   vtbh = (u16*)  (base + 80*MB);
    u16*   qhbl = (u16*)  (base + 88*MB);
    u16*   khbl = (u16*)  (base + 96*MB);
    u16*   vtbl = (u16*)  (base + 104*MB);
    u16*   xhi  = (u16*)  (base + 112*MB);
    u16*   xlo  = (u16*)  (base + 120*MB);
    u16*   xb   = (u16*)  (base + 128*MB);
    u16*   wTh  = (u16*)  (base + 136*MB);
    u16*   wTl  = (u16*)  (base + 144*MB);
    u16*   w2Th = (u16*)  (base + 152*MB);
    u16*   w2Tl = (u16*)  (base + 160*MB);
    // grouped MoE regions
    u16*   W1Th = (u16*)  (base + 32*MB);      // 32-96
    u16*   W1Tl = (u16*)  (base + 136*MB);     // 136-200
    u16*   W2Thb= (u16*)  (base + 200*MB);     // 200-264
    u16*   W2Tlb= (u16*)  (base + 264*MB);     // 264-328
    u16*   HeH  = (u16*)  (base + 328*MB);     // 328-392
    u16*   HeL  = (u16*)  (base + 392*MB);     // 392-456
    u16*   He16g= (u16*)  (base + 200*MB);     // L1 W2T
    // routing data
    char*  rbase = base + (size_t)458*MB;
    int*   e0b  = (int*)  rbase;
    int*   e1b  = e0b + 4096;
    float* w0b  = (float*)(e1b + 4096);
    float* w1b  = w0b + 4096;
    int*   tok  = (int*)(w1b + 4096);
    int*   slA  = tok + 8192;
    int*   slB  = slA + 4096;
    int*   cnts = slB + 4096;
    int*   offs = cnts + 8;

    float* hf = (float*)d_out;
    const size_t HTOK = (size_t)4096*1024;

    const size_t WSTRIDE = (size_t)1024*1024;
    const size_t ESTRIDE = (size_t)1024*4096;

    // =================== LAYER 0 (split-bf16: fp32-grade h1) ===================
    {
        init_split<<<16384,256,0,stream>>>(x, hf, xhi, xlo, (int)HTOK);
        gating_top2<<<1024,256,0,stream>>>(hf, Wg, e0b,e1b,w0b,w1b);
        routing_kernel<<<1,512,0,stream>>>(e0b,e1b, tok,slA,slB, cnts,offs);

        transpose_split<<<dim3(32,32),dim3(32,8),0,stream>>>(Wq, wTh,           wTl,           1024,1024);
        transpose_split<<<dim3(32,32),dim3(32,8),0,stream>>>(Wk, wTh + 1048576, wTl + 1048576, 1024,1024);
        transpose_split<<<dim3(32,32),dim3(32,8),0,stream>>>(Wv, wTh + 2097152, wTl + 2097152, 1024,1024);
        mgemm_s<0><<<dim3(24,32),256,0,stream>>>(xhi, xlo, wTh, wTl, qkvf, 4096,3072,1024,3072);

        qknorm_out<<<1024,256,0,stream>>>(qkvf, qs, ks, qhbh, qhbl, khbh, khbl, 1);
        transpose_v<<<dim3(64,2,32),dim3(32,8),0,stream>>>(qkvf, vtbh, vtbl, 1);
        attn_flash<1><<<dim3(32,32),256,0,stream>>>(qhbh, qhbl, khbh, khbl, vtbh, vtbl, afhi, aflo);

        transpose_split<<<dim3(32,32),dim3(32,8),0,stream>>>(Wo, w2Th, w2Tl, 1024,1024);
        mgemm_s<1><<<dim3(8,32),256,0,stream>>>(afhi, aflo, w2Th, w2Tl, hf, 4096,1024,1024,1024);

        transpose_split_z<<<dim3(128,32,8),dim3(32,8),0,stream>>>(W1, W1Th, W1Tl, 1024,4096, ESTRIDE, (size_t)4096*1024);
        transpose_split_z<<<dim3(32,128,8),dim3(32,8),0,stream>>>(W2, W2Thb, W2Tlb, 4096,1024, ESTRIDE, (size_t)1024*4096);
        mgemm_gs<true ><<<dim3(32,32,8),256,0,stream>>>(xhi, xlo, W1Th, W1Tl, nullptr, HeH, HeL, b1, tok,cnts,offs, 4096,1024);
        mgemm_gs<false><<<dim3(8,32,8),256,0,stream>>>(HeH, HeL, W2Thb, W2Tlb, Mo, nullptr,nullptr, nullptr, tok,cnts,offs, 1024,4096);

        combine_kernel<<<4096,256,0,stream>>>(hf, Mo, slA,slB, e0b,e1b, w0b,w1b, b2, xb);
    }

    // =================== LAYER 1 (plain bf16) ===================
    {
        gating_top2<<<1024,256,0,stream>>>(hf, Wg + (size_t)1024*8, e0b,e1b,w0b,w1b);
        routing_kernel<<<1,512,0,stream>>>(e0b,e1b, tok,slA,slB, cnts,offs);

        transpose_cvt<<<dim3(32,32),dim3(32,8),0,stream>>>(Wq + WSTRIDE, wTh,           1024,1024);
        transpose_cvt<<<dim3(32,32),dim3(32,8),0,stream>>>(Wk + WSTRIDE, wTh + 1048576, 1024,1024);
        transpose_cvt<<<dim3(32,32),dim3(32,8),0,stream>>>(Wv + WSTRIDE, wTh + 2097152, 1024,1024);
        mgemm<0><<<dim3(24,32),256,0,stream>>>(xb, wTh, qkvf, nullptr, nullptr,nullptr, 4096,3072,1024,3072);

        qknorm_out<<<1024,256,0,stream>>>(qkvf, qs + 64, ks + 64, qhbh, nullptr, khbh, nullptr, 0);
        transpose_v<<<dim3(64,2,32),dim3(32,8),0,stream>>>(qkvf, vtbh, nullptr, 0);
        attn_flash<0><<<dim3(32,32),256,0,stream>>>(qhbh, nullptr, khbh, nullptr, vtbh, nullptr, afhi, nullptr);

        transpose_cvt<<<dim3(32,32),dim3(32,8),0,stream>>>(Wo + WSTRIDE, w2Th, 1024,1024);
        mgemm<1><<<dim3(8,32),256,0,stream>>>(afhi, w2Th, hf, nullptr, nullptr,nullptr, 4096,1024,1024,1024);

        transpose_cvt_z<<<dim3(128,32,8),dim3(32,8),0,stream>>>(W1 + (size_t)8*ESTRIDE, W1Th, 1024,4096, ESTRIDE, (size_t)4096*1024);
        transpose_cvt_z<<<dim3(32,128,8),dim3(32,8),0,stream>>>(W2 + (size_t)8*ESTRIDE, He16g, 4096,1024, ESTRIDE, (size_t)1024*4096);
        mgemm_gp<true ><<<dim3(32,32,8),256,0,stream>>>(xb, W1Th, nullptr, (u16*)HeH, b1 + (size_t)8*4096, tok,cnts,offs, 4096,1024);
        mgemm_gp<false><<<dim3(8,32,8),256,0,stream>>>((u16*)HeH, He16g, Mo, nullptr, nullptr, tok,cnts,offs, 1024,4096);

        combine_kernel<<<4096,256,0,stream>>>(hf, Mo, slA,slB, e0b,e1b, w0b,w1b, b2 + (size_t)8*1024, nullptr);
    }
}

// Round 24
// 1925.735 us; speedup vs baseline: 1.7860x; 1.0039x over previous
//
#include <hip/hip_runtime.h>
#include <cstdint>

typedef unsigned short u16;
typedef __attribute__((ext_vector_type(4))) float f32x4;
typedef __attribute__((ext_vector_type(8))) __bf16 bf16x8;

#define DEV static __device__ __forceinline__

DEV u16 f2b(float f){
    unsigned int u = __builtin_bit_cast(unsigned int, f);
    u += 0x7fffu + ((u >> 16) & 1u);
    return (u16)(u >> 16);
}
DEV float b2f(u16 u){ return __builtin_bit_cast(float, (unsigned int)u << 16); }
DEV float gelu_f(float x){
    float x3 = x*x*x;
    return 0.5f*x*(1.f + tanhf(0.7978845608f*(x + 0.044715f*x3)));
}

DEV void gload16(const u16* g, u16* l){
    __builtin_amdgcn_global_load_lds(
        (const __attribute__((address_space(1))) unsigned int*)g,
        (__attribute__((address_space(3))) unsigned int*)l,
        16, 0, 0);
}

// ---------------- MFMA GEMM plain (verified) ----------------
template<int MODE>
__global__ __launch_bounds__(256) void mgemm(
    const u16* __restrict__ A, const u16* __restrict__ Bt,
    float* __restrict__ Cf, u16* __restrict__ Cb,
    const float* __restrict__ bias, const float* __restrict__ rowscale,
    int M, int N, int K, int ldc){
    int nb = blockIdx.x, mb = blockIdx.y;
    int tid = threadIdx.x, lane = tid & 63, w = tid >> 6;
    int rr = lane & 15, hi = lane >> 4;
    int wm = (w >> 1)*64, wn = (w & 1)*64;
    __shared__ u16 As[128*64];
    __shared__ u16 Bs[128*64];
    int sw_r = (rr & 7) * 8;
    int ce = (((lane&7) ^ (lane>>3)))*8;
    const u16* ap[4]; const u16* bp[4];
    u16* adst[4]; u16* bdst[4];
    #pragma unroll
    for (int p=0;p<4;++p){
        int r = (w*4+p)*8 + (lane>>3);
        ap[p] = A  + (size_t)(mb*128 + r)*K + ce;
        bp[p] = Bt + (size_t)(nb*128 + r)*K + ce;
        adst[p] = &As[(w*4+p)*512];
        bdst[p] = &Bs[(w*4+p)*512];
    }
    f32x4 acc[4][4];
    #pragma unroll
    for (int mt=0;mt<4;++mt)
        #pragma unroll
        for (int nt=0;nt<4;++nt) acc[mt][nt] = (f32x4){0.f,0.f,0.f,0.f};

    for (int k0=0; k0<K; k0+=64){
        #pragma unroll
        for (int p=0;p<4;++p){
            gload16(ap[p] + k0, adst[p]);
            gload16(bp[p] + k0, bdst[p]);
        }
        __syncthreads();
        #pragma unroll
        for (int kc=0;kc<2;++kc){
            int kk = (kc*32 + hi*8) ^ sw_r;
            bf16x8 af[4], bfv[4];
            #pragma unroll
            for (int mt=0;mt<4;++mt) af[mt]  = *(const bf16x8*)&As[(wm+mt*16+rr)*64 + kk];
            #pragma unroll
            for (int nt=0;nt<4;++nt) bfv[nt] = *(const bf16x8*)&Bs[(wn+nt*16+rr)*64 + kk];
            #pragma unroll
            for (int mt=0;mt<4;++mt)
                #pragma unroll
                for (int nt=0;nt<4;++nt)
                    acc[mt][nt] = __builtin_amdgcn_mfma_f32_16x16x32_bf16(af[mt], bfv[nt], acc[mt][nt], 0,0,0);
        }
        __syncthreads();
    }
    #pragma unroll
    for (int mt=0;mt<4;++mt){
        #pragma unroll
        for (int j=0;j<4;++j){
            int m = wm + mt*16 + hi*4 + j;
            size_t orow = (size_t)(mb*128 + m);
            #pragma unroll
            for (int nt=0;nt<4;++nt){
                int col = nb*128 + wn + nt*16 + rr;
                float v = acc[mt][nt][j];
                if (MODE == 0)      Cf[orow*ldc + col] = v;
                else if (MODE == 1) Cf[orow*ldc + col] += v;
            }
        }
    }
}

// ---------------- FUSED split-bf16 GEMM (dense, verified) ----------------
template<int MODE>
__global__ __launch_bounds__(256) void mgemm_s(
    const u16* __restrict__ Ah, const u16* __restrict__ Al,
    const u16* __restrict__ Bth, const u16* __restrict__ Btl,
    float* __restrict__ Cf, int M, int N, int K, int ldc){
    int nb = blockIdx.x, mb = blockIdx.y;
    int tid = threadIdx.x, lane = tid & 63, w = tid >> 6;
    int rr = lane & 15, hi = lane >> 4;
    int wm = (w >> 1)*64, wn = (w & 1)*64;
    __shared__ u16 Ash[128*64];
    __shared__ u16 Asl[128*64];
    __shared__ u16 Bsh[128*64];
    __shared__ u16 Bsl[128*64];
    int sw_r = (rr & 7) * 8;
    int ce = (((lane&7) ^ (lane>>3)))*8;
    const u16* ahp[4]; const u16* alp[4]; const u16* bhp[4]; const u16* blp[4];
    u16 *ahd[4], *ald[4], *bhd[4], *bld[4];
    #pragma unroll
    for (int p=0;p<4;++p){
        int r = (w*4+p)*8 + (lane>>3);
        size_t ao = (size_t)(mb*128 + r)*K + ce;
        size_t bo = (size_t)(nb*128 + r)*K + ce;
        ahp[p] = Ah + ao;  alp[p] = Al + ao;
        bhp[p] = Bth + bo; blp[p] = Btl + bo;
        ahd[p] = &Ash[(w*4+p)*512]; ald[p] = &Asl[(w*4+p)*512];
        bhd[p] = &Bsh[(w*4+p)*512]; bld[p] = &Bsl[(w*4+p)*512];
    }
    f32x4 acc[4][4];
    #pragma unroll
    for (int mt=0;mt<4;++mt)
        #pragma unroll
        for (int nt=0;nt<4;++nt) acc[mt][nt] = (f32x4){0.f,0.f,0.f,0.f};

    for (int k0=0; k0<K; k0+=64){
        #pragma unroll
        for (int p=0;p<4;++p){
            gload16(ahp[p] + k0, ahd[p]);
            gload16(alp[p] + k0, ald[p]);
            gload16(bhp[p] + k0, bhd[p]);
            gload16(blp[p] + k0, bld[p]);
        }
        __syncthreads();
        #pragma unroll
        for (int kc=0;kc<2;++kc){
            int kk = (kc*32 + hi*8) ^ sw_r;
            bf16x8 afh[4], afl[4], bfh[4], bfl[4];
            #pragma unroll
            for (int mt=0;mt<4;++mt){
                afh[mt] = *(const bf16x8*)&Ash[(wm+mt*16+rr)*64 + kk];
                afl[mt] = *(const bf16x8*)&Asl[(wm+mt*16+rr)*64 + kk];
            }
            #pragma unroll
            for (int nt=0;nt<4;++nt){
                bfh[nt] = *(const bf16x8*)&Bsh[(wn+nt*16+rr)*64 + kk];
                bfl[nt] = *(const bf16x8*)&Bsl[(wn+nt*16+rr)*64 + kk];
            }
            #pragma unroll
            for (int mt=0;mt<4;++mt)
                #pragma unroll
                for (int nt=0;nt<4;++nt){
                    acc[mt][nt] = __builtin_amdgcn_mfma_f32_16x16x32_bf16(afh[mt], bfh[nt], acc[mt][nt], 0,0,0);
                    acc[mt][nt] = __builtin_amdgcn_mfma_f32_16x16x32_bf16(afh[mt], bfl[nt], acc[mt][nt], 0,0,0);
                    acc[mt][nt] = __builtin_amdgcn_mfma_f32_16x16x32_bf16(afl[mt], bfh[nt], acc[mt][nt], 0,0,0);
                }
        }
        __syncthreads();
    }
    #pragma unroll
    for (int mt=0;mt<4;++mt){
        #pragma unroll
        for (int j=0;j<4;++j){
            int m = wm + mt*16 + hi*4 + j;
            size_t orow = (size_t)(mb*128 + m);
            #pragma unroll
            for (int nt=0;nt<4;++nt){
                int col = nb*128 + wn + nt*16 + rr;
                float v = acc[mt][nt][j];
                if (MODE == 0)      Cf[orow*ldc + col] = v;
                else if (MODE == 1) Cf[orow*ldc + col] += v;
            }
        }
    }
}

// ---------------- GROUPED split expert GEMM (r20 grid order: nb = blockIdx.x) ----------------
template<bool UP>
__global__ __launch_bounds__(256) void mgemm_gs(
    const u16* __restrict__ Ah, const u16* __restrict__ Al,
    const u16* __restrict__ Bth, const u16* __restrict__ Btl,
    float* __restrict__ Cf, u16* __restrict__ OutH, u16* __restrict__ OutL,
    const float* __restrict__ b1all,
    const int* __restrict__ tok, const int* __restrict__ counts, const int* __restrict__ offs,
    int N, int K){
    int e = blockIdx.z;
    int cnt = counts[e];
    int nb = blockIdx.x, mb = blockIdx.y;
    if (mb*128 >= cnt) return;
    int slot0 = offs[e];
    const u16* Bh = Bth + (size_t)e*N*K;
    const u16* Bl = Btl + (size_t)e*N*K;
    int tid = threadIdx.x, lane = tid & 63, w = tid >> 6;
    int rr = lane & 15, hi = lane >> 4;
    int wm = (w >> 1)*64, wn = (w & 1)*64;
    __shared__ u16 Ash[128*64];
    __shared__ u16 Asl[128*64];
    __shared__ u16 Bsh[128*64];
    __shared__ u16 Bsl[128*64];
    int sw_r = (rr & 7) * 8;
    int ce = (((lane&7) ^ (lane>>3)))*8;
    const u16* ahp[4]; const u16* alp[4]; const u16* bhp[4]; const u16* blp[4];
    u16 *ahd[4], *ald[4], *bhd[4], *bld[4];
    #pragma unroll
    for (int p=0;p<4;++p){
        int r = (w*4+p)*8 + (lane>>3);
        int lr = mb*128 + r;
        int lc = lr < cnt ? lr : (cnt-1);
        size_t arow = UP ? (size_t)tok[slot0 + lc] : (size_t)(slot0 + lc);
        ahp[p] = Ah + arow*K + ce;
        alp[p] = Al + arow*K + ce;
        bhp[p] = Bh + (size_t)(nb*128 + r)*K + ce;
        blp[p] = Bl + (size_t)(nb*128 + r)*K + ce;
        ahd[p] = &Ash[(w*4+p)*512]; ald[p] = &Asl[(w*4+p)*512];
        bhd[p] = &Bsh[(w*4+p)*512]; bld[p] = &Bsl[(w*4+p)*512];
    }
    f32x4 acc[4][4];
    #pragma unroll
    for (int mt=0;mt<4;++mt)
        #pragma unroll
        for (int nt=0;nt<4;++nt) acc[mt][nt] = (f32x4){0.f,0.f,0.f,0.f};

    for (int k0=0; k0<K; k0+=64){
        #pragma unroll
        for (int p=0;p<4;++p){
            gload16(ahp[p] + k0, ahd[p]);
            gload16(alp[p] + k0, ald[p]);
            gload16(bhp[p] + k0, bhd[p]);
            gload16(blp[p] + k0, bld[p]);
        }
        __syncthreads();
        #pragma unroll
        for (int kc=0;kc<2;++kc){
            int kk = (kc*32 + hi*8) ^ sw_r;
            bf16x8 afh[4], afl[4], bfh[4], bfl[4];
            #pragma unroll
            for (int mt=0;mt<4;++mt){
                afh[mt] = *(const bf16x8*)&Ash[(wm+mt*16+rr)*64 + kk];
                afl[mt] = *(const bf16x8*)&Asl[(wm+mt*16+rr)*64 + kk];
            }
            #pragma unroll
            for (int nt=0;nt<4;++nt){
                bfh[nt] = *(const bf16x8*)&Bsh[(wn+nt*16+rr)*64 + kk];
                bfl[nt] = *(const bf16x8*)&Bsl[(wn+nt*16+rr)*64 + kk];
            }
            #pragma unroll
            for (int mt=0;mt<4;++mt)
                #pragma unroll
                for (int nt=0;nt<4;++nt){
                    acc[mt][nt] = __builtin_amdgcn_mfma_f32_16x16x32_bf16(afh[mt], bfh[nt], acc[mt][nt], 0,0,0);
                    acc[mt][nt] = __builtin_amdgcn_mfma_f32_16x16x32_bf16(afh[mt], bfl[nt], acc[mt][nt], 0,0,0);
                    acc[mt][nt] = __builtin_amdgcn_mfma_f32_16x16x32_bf16(afl[mt], bfh[nt], acc[mt][nt], 0,0,0);
                }
        }
        __syncthreads();
    }
    const float* b1e = UP ? (b1all + (size_t)e*N) : nullptr;
    #pragma unroll
    for (int mt=0;mt<4;++mt){
        #pragma unroll
        for (int j=0;j<4;++j){
            int m = wm + mt*16 + hi*4 + j;
            int lr = mb*128 + m;
            if (lr >= cnt) continue;
            size_t orow = (size_t)(slot0 + lr);
            #pragma unroll
            for (int nt=0;nt<4;++nt){
                int col = nb*128 + wn + nt*16 + rr;
                float v = acc[mt][nt][j];
                if (UP){
                    float g = gelu_f(v + b1e[col]);
                    u16 h = f2b(g);
                    OutH[orow*N + col] = h;
                    OutL[orow*N + col] = f2b(g - b2f(h));
                } else {
                    Cf[orow*N + col] = v;
                }
            }
        }
    }
}

// ---------------- GROUPED plain expert GEMM (L1; r20 grid order) ----------------
template<bool UP>
__global__ __launch_bounds__(256) void mgemm_gp(
    const u16* __restrict__ A, const u16* __restrict__ Bt,
    float* __restrict__ Cf, u16* __restrict__ Cb, const float* __restrict__ b1all,
    const int* __restrict__ tok, const int* __restrict__ counts, const int* __restrict__ offs,
    int N, int K){
    int e = blockIdx.z;
    int cnt = counts[e];
    int nb = blockIdx.x, mb = blockIdx.y;
    if (mb*128 >= cnt) return;
    int slot0 = offs[e];
    const u16* Bte = Bt + (size_t)e*N*K;
    int tid = threadIdx.x, lane = tid & 63, w = tid >> 6;
    int rr = lane & 15, hi = lane >> 4;
    int wm = (w >> 1)*64, wn = (w & 1)*64;
    __shared__ u16 As[128*64];
    __shared__ u16 Bs[128*64];
    int sw_r = (rr & 7) * 8;
    int ce = (((lane&7) ^ (lane>>3)))*8;
    const u16* aptr[4]; const u16* bptr[4];
    u16 *adst[4], *bdst[4];
    #pragma unroll
    for (int p=0;p<4;++p){
        int r = (w*4+p)*8 + (lane>>3);
        int lr = mb*128 + r;
        int lc = lr < cnt ? lr : (cnt-1);
        size_t arow = UP ? (size_t)tok[slot0 + lc] : (size_t)(slot0 + lc);
        aptr[p] = A  + arow*K + ce;
        bptr[p] = Bte + (size_t)(nb*128 + r)*K + ce;
        adst[p] = &As[(w*4+p)*512];
        bdst[p] = &Bs[(w*4+p)*512];
    }
    f32x4 acc[4][4];
    #pragma unroll
    for (int mt=0;mt<4;++mt)
        #pragma unroll
        for (int nt=0;nt<4;++nt) acc[mt][nt] = (f32x4){0.f,0.f,0.f,0.f};

    for (int k0=0; k0<K; k0+=64){
        #pragma unroll
        for (int p=0;p<4;++p){
            gload16(aptr[p] + k0, adst[p]);
            gload16(bptr[p] + k0, bdst[p]);
        }
        __syncthreads();
        #pragma unroll
        for (int kc=0;kc<2;++kc){
            int kk = (kc*32 + hi*8) ^ sw_r;
            bf16x8 af[4], bfv[4];
            #pragma unroll
            for (int mt=0;mt<4;++mt) af[mt]  = *(const bf16x8*)&As[(wm+mt*16+rr)*64 + kk];
            #pragma unroll
            for (int nt=0;nt<4;++nt) bfv[nt] = *(const bf16x8*)&Bs[(wn+nt*16+rr)*64 + kk];
            #pragma unroll
            for (int mt=0;mt<4;++mt)
                #pragma unroll
                for (int nt=0;nt<4;++nt)
                    acc[mt][nt] = __builtin_amdgcn_mfma_f32_16x16x32_bf16(af[mt], bfv[nt], acc[mt][nt], 0,0,0);
        }
        __syncthreads();
    }
    const float* b1e = UP ? (b1all + (size_t)e*N) : nullptr;
    #pragma unroll
    for (int mt=0;mt<4;++mt){
        #pragma unroll
        for (int j=0;j<4;++j){
            int m = wm + mt*16 + hi*4 + j;
            int lr = mb*128 + m;
            if (lr >= cnt) continue;
            size_t orow = (size_t)(slot0 + lr);
            #pragma unroll
            for (int nt=0;nt<4;++nt){
                int col = nb*128 + wn + nt*16 + rr;
                float v = acc[mt][nt][j];
                if (UP) Cb[orow*N + col] = f2b(gelu_f(v + b1e[col]));
                else    Cf[orow*N + col] = v;
            }
        }
    }
}

// ---------------- elementwise / transpose helpers ----------------
__global__ __launch_bounds__(256) void init_split(const float* __restrict__ x,
                                                  float* __restrict__ hf,
                                                  u16* __restrict__ oh, u16* __restrict__ ol, int n){
    int i = blockIdx.x*256 + threadIdx.x;
    if (i < n){
        float v = x[i];
        hf[i] = v;
        u16 h = f2b(v);
        oh[i] = h;
        ol[i] = f2b(v - b2f(h));
    }
}

__global__ void transpose_cvt(const float* __restrict__ in, u16* __restrict__ out, int R, int C){
    __shared__ float t[32][33];
    int c0 = blockIdx.x*32, r0 = blockIdx.y*32;
    int tx = threadIdx.x, ty = threadIdx.y;
    #pragma unroll
    for (int i=0;i<4;++i) t[ty+i*8][tx] = in[(size_t)(r0+ty+i*8)*C + c0+tx];
    __syncthreads();
    #pragma unroll
    for (int i=0;i<4;++i) out[(size_t)(c0+ty+i*8)*R + r0+tx] = f2b(t[tx][ty+i*8]);
}

__global__ void transpose_cvt_z(const float* __restrict__ in, u16* __restrict__ out, int R, int C,
                                size_t inzs, size_t outzs){
    in += (size_t)blockIdx.z * inzs;
    out += (size_t)blockIdx.z * outzs;
    __shared__ float t[32][33];
    int c0 = blockIdx.x*32, r0 = blockIdx.y*32;
    int tx = threadIdx.x, ty = threadIdx.y;
    #pragma unroll
    for (int i=0;i<4;++i) t[ty+i*8][tx] = in[(size_t)(r0+ty+i*8)*C + c0+tx];
    __syncthreads();
    #pragma unroll
    for (int i=0;i<4;++i) out[(size_t)(c0+ty+i*8)*R + r0+tx] = f2b(t[tx][ty+i*8]);
}

__global__ void transpose_split(const float* __restrict__ in, u16* __restrict__ oh,
                                u16* __restrict__ ol, int R, int C){
    __shared__ float t[32][33];
    int c0 = blockIdx.x*32, r0 = blockIdx.y*32;
    int tx = threadIdx.x, ty = threadIdx.y;
    #pragma unroll
    for (int i=0;i<4;++i) t[ty+i*8][tx] = in[(size_t)(r0+ty+i*8)*C + c0+tx];
    __syncthreads();
    #pragma unroll
    for (int i=0;i<4;++i){
        float v = t[tx][ty+i*8];
        size_t idx = (size_t)(c0+ty+i*8)*R + r0+tx;
        u16 h = f2b(v);
        oh[idx] = h;
        ol[idx] = f2b(v - b2f(h));
    }
}

__global__ void transpose_split_z(const float* __restrict__ in, u16* __restrict__ oh,
                                  u16* __restrict__ ol, int R, int C,
                                  size_t inzs, size_t outzs){
    in += (size_t)blockIdx.z * inzs;
    oh += (size_t)blockIdx.z * outzs;
    ol += (size_t)blockIdx.z * outzs;
    __shared__ float t[32][33];
    int c0 = blockIdx.x*32, r0 = blockIdx.y*32;
    int tx = threadIdx.x, ty = threadIdx.y;
    #pragma unroll
    for (int i=0;i<4;++i) t[ty+i*8][tx] = in[(size_t)(r0+ty+i*8)*C + c0+tx];
    __syncthreads();
    #pragma unroll
    for (int i=0;i<4;++i){
        float v = t[tx][ty+i*8];
        size_t idx = (size_t)(c0+ty+i*8)*R + r0+tx;
        u16 h = f2b(v);
        oh[idx] = h;
        ol[idx] = f2b(v - b2f(h));
    }
}

__global__ __launch_bounds__(256) void combine_kernel(
    float* __restrict__ hf, const float* __restrict__ Mo,
    const int* __restrict__ slA, const int* __restrict__ slB,
    const int* __restrict__ e0, const int* __restrict__ e1,
    const float* __restrict__ w0, const float* __restrict__ w1,
    const float* __restrict__ b2l, u16* __restrict__ xbout){
    int t = blockIdx.x;
    int n = threadIdx.x*4;
    int sA = slA[t], sB = slB[t];
    const float* bA = b2l + e0[t]*1024;
    const float* bB = b2l + e1[t]*1024;
    float ww0 = w0[t], ww1 = w1[t];
    const float* pA = Mo + (size_t)sA*1024 + n;
    const float* pB = Mo + (size_t)sB*1024 + n;
    float* yp = hf + (size_t)t*1024 + n;
    u16* xp = xbout ? (xbout + (size_t)t*1024 + n) : nullptr;
    #pragma unroll
    for (int k=0;k<4;++k){
        float v = yp[k] + (pA[k] + bA[n+k])*ww0 + (pB[k] + bB[n+k])*ww1;
        yp[k] = v;
        if (xbout) xp[k] = f2b(v);
    }
}

__global__ __launch_bounds__(256) void qknorm_out(
    const float* __restrict__ qkvf, const float* __restrict__ qs, const float* __restrict__ ks,
    u16* __restrict__ qh, u16* __restrict__ ql, u16* __restrict__ kh, u16* __restrict__ kl,
    int split){
    int t = blockIdx.x*4 + (threadIdx.x>>6);
    int lane = threadIdx.x & 63;
    int h = lane>>2, d0 = (lane&3)*16;
    int b = t>>11, s = t & 2047;
    const float* qp = qkvf + (size_t)t*3072 + h*64 + d0;
    const float* kp = qp + 1024;
    float qv[16], kv[16];
    float sq = 0.f, sk = 0.f;
    #pragma unroll
    for (int i=0;i<16;++i){
        qv[i] = qp[i]; kv[i] = kp[i];
        sq += qv[i]*qv[i];  sk += kv[i]*kv[i];
    }
    sq += __shfl_xor(sq,1); sq += __shfl_xor(sq,2);
    sk += __shfl_xor(sk,1); sk += __shfl_xor(sk,2);
    float rq = rsqrtf(sq + 1e-6f) * 10.f;
    float rk = rsqrtf(sk + 1e-6f);
    size_t ob = ((size_t)(b*16+h)*2048 + s)*64 + d0;
    #pragma unroll
    for (int i=0;i<16;++i){
        float qn = qv[i]*rq*qs[d0+i];
        float kn = kv[i]*rk*ks[d0+i];
        u16 hq = f2b(qn), hk = f2b(kn);
        qh[ob+i] = hq; kh[ob+i] = hk;
        if (split){
            ql[ob+i] = f2b(qn - b2f(hq));
            kl[ob+i] = f2b(kn - b2f(hk));
        }
    }
}

__global__ void transpose_v(const float* __restrict__ qkvf, u16* __restrict__ vh,
                            u16* __restrict__ vl, int split){
    __shared__ float t[32][33];
    int s0 = blockIdx.x*32, d0 = blockIdx.y*32;
    int bh = blockIdx.z, b = bh>>4, h = bh&15;
    int tx = threadIdx.x, ty = threadIdx.y;
    #pragma unroll
    for (int i=0;i<4;++i)
        t[ty+i*8][tx] = qkvf[(size_t)(b*2048 + s0+ty+i*8)*3072 + 2048 + h*64 + d0 + tx];
    __syncthreads();
    #pragma unroll
    for (int i=0;i<4;++i){
        float v = t[tx][ty+i*8];
        size_t idx = ((size_t)bh*64 + d0+ty+i*8)*2048 + s0 + tx;
        u16 hv = f2b(v);
        vh[idx] = hv;
        if (split) vl[idx] = f2b(v - b2f(hv));
    }
}

// ---------------- MFMA flash attention (causal); gload_lds K/V staging ----------------
template<int SPLIT>
__global__ __launch_bounds__(256) void attn_flash(
    const u16* __restrict__ qh, const u16* __restrict__ ql,
    const u16* __restrict__ kh, const u16* __restrict__ kl,
    const u16* __restrict__ vth, const u16* __restrict__ vtl,
    u16* __restrict__ oh, u16* __restrict__ ol){
    int qt = (int)gridDim.x - 1 - (int)blockIdx.x;   // tail-first (LPT)
    int bh = blockIdx.y;
    int tid = threadIdx.x, w = tid>>6, lane = tid & 63;
    int rr = lane & 15, hi = lane >> 4;
    __shared__ u16 Ksh[64*64];
    __shared__ u16 Vsh[64*64];
    __shared__ u16 Ksl[SPLIT ? 64*64 : 8];
    __shared__ u16 Vsl[SPLIT ? 64*64 : 8];
    __shared__ u16 Ps [4][16*72];
    __shared__ u16 Psl[SPLIT ? 4 : 1][16*72];
    int sw_r = (rr&7)*8;
    // gload staging: segment s = w*2+p covers rows s*8+(lane>>3); swizzled source col
    int ce = ((lane&7) ^ (lane>>3))*8;
    int srow[2]; u16 *kd[2], *vd[2], *kld[2], *vld[2];
    #pragma unroll
    for (int p=0;p<2;++p){
        int s = w*2 + p;
        srow[p] = s*8 + (lane>>3);
        kd[p] = &Ksh[s*512]; vd[p] = &Vsh[s*512];
        if (SPLIT){ kld[p] = &Ksl[s*512]; vld[p] = &Vsl[s*512]; }
    }

    bf16x8 qfh[2], qfl[2];
    {
        size_t qo = (((size_t)bh*2048) + qt*64 + w*16 + rr)*64 + hi*8;
        qfh[0] = *(const bf16x8*)(qh + qo);
        qfh[1] = *(const bf16x8*)(qh + qo + 32);
        if (SPLIT){
            qfl[0] = *(const bf16x8*)(ql + qo);
            qfl[1] = *(const bf16x8*)(ql + qo + 32);
        }
    }
    f32x4 oacc[4];
    #pragma unroll
    for (int dt=0;dt<4;++dt) oacc[dt] = (f32x4){0.f,0.f,0.f,0.f};
    float mrow[4] = {-3e38f,-3e38f,-3e38f,-3e38f};
    float lrow[4] = {0.f,0.f,0.f,0.f};

    for (int kt=0; kt<=qt; ++kt){
        #pragma unroll
        for (int p=0;p<2;++p){
            int r = srow[p];
            size_t koff = (((size_t)bh*2048) + kt*64 + r)*64 + ce;
            size_t voff = ((size_t)bh*64 + r)*2048 + kt*64 + ce;
            gload16(kh + koff, kd[p]);
            gload16(vth + voff, vd[p]);
            if (SPLIT){
                gload16(kl + koff, kld[p]);
                gload16(vtl + voff, vld[p]);
            }
        }
        __syncthreads();
        f32x4 sacc[4];
        #pragma unroll
        for (int nt=0;nt<4;++nt) sacc[nt] = (f32x4){0.f,0.f,0.f,0.f};
        #pragma unroll
        for (int kc=0;kc<2;++kc){
            int kk = (kc*32 + hi*8) ^ sw_r;
            #pragma unroll
            for (int nt=0;nt<4;++nt){
                bf16x8 kf = *(const bf16x8*)&Ksh[(nt*16+rr)*64 + kk];
                sacc[nt] = __builtin_amdgcn_mfma_f32_16x16x32_bf16(qfh[kc], kf, sacc[nt], 0,0,0);
                if (SPLIT){
                    bf16x8 kf2 = *(const bf16x8*)&Ksl[(nt*16+rr)*64 + kk];
                    sacc[nt] = __builtin_amdgcn_mfma_f32_16x16x32_bf16(qfh[kc], kf2, sacc[nt], 0,0,0);
                    sacc[nt] = __builtin_amdgcn_mfma_f32_16x16x32_bf16(qfl[kc], kf,  sacc[nt], 0,0,0);
                }
            }
        }
        if (kt == qt){
            #pragma unroll
            for (int nt=0;nt<4;++nt)
                #pragma unroll
                for (int j=0;j<4;++j)
                    if (nt*16 + rr > w*16 + hi*4 + j) sacc[nt][j] = -3e38f;
        }
        float corr[4];
        #pragma unroll
        for (int j=0;j<4;++j){
            float t = fmaxf(fmaxf(sacc[0][j],sacc[1][j]), fmaxf(sacc[2][j],sacc[3][j]));
            t = fmaxf(t, __shfl_xor(t,1));
            t = fmaxf(t, __shfl_xor(t,2));
            t = fmaxf(t, __shfl_xor(t,4));
            t = fmaxf(t, __shfl_xor(t,8));
            float mn = fmaxf(mrow[j], t);
            corr[j] = __expf(mrow[j] - mn);
            mrow[j] = mn;
        }
        float rsum[4] = {0.f,0.f,0.f,0.f};
        #pragma unroll
        for (int nt=0;nt<4;++nt)
            #pragma unroll
            for (int j=0;j<4;++j){
                float p = __expf(sacc[nt][j] - mrow[j]);
                sacc[nt][j] = p;
                rsum[j] += p;
            }
        #pragma unroll
        for (int j=0;j<4;++j){
            rsum[j] += __shfl_xor(rsum[j],1);
            rsum[j] += __shfl_xor(rsum[j],2);
            rsum[j] += __shfl_xor(rsum[j],4);
            rsum[j] += __shfl_xor(rsum[j],8);
            lrow[j] = lrow[j]*corr[j] + rsum[j];
        }
        #pragma unroll
        for (int dt=0;dt<4;++dt)
            #pragma unroll
            for (int j=0;j<4;++j) oacc[dt][j] *= corr[j];
        u16* pw = Ps[w];
        #pragma unroll
        for (int nt=0;nt<4;++nt)
            #pragma unroll
            for (int j=0;j<4;++j){
                float p = sacc[nt][j];
                u16 ph = f2b(p);
                pw[(hi*4+j)*72 + nt*16 + rr] = ph;
                if (SPLIT) Psl[w][(hi*4+j)*72 + nt*16 + rr] = f2b(p - b2f(ph));
            }
        __syncthreads();
        #pragma unroll
        for (int kc=0;kc<2;++kc){
            bf16x8 pf = *(const bf16x8*)&pw[rr*72 + kc*32 + hi*8];
            bf16x8 pfl;
            if (SPLIT) pfl = *(const bf16x8*)&Psl[w][rr*72 + kc*32 + hi*8];
            int vk = (kc*32 + hi*8) ^ sw_r;
            #pragma unroll
            for (int dt=0;dt<4;++dt){
                bf16x8 vf = *(const bf16x8*)&Vsh[(dt*16+rr)*64 + vk];
                oacc[dt] = __builtin_amdgcn_mfma_f32_16x16x32_bf16(pf, vf, oacc[dt], 0,0,0);
                if (SPLIT){
                    bf16x8 vf2 = *(const bf16x8*)&Vsl[(dt*16+rr)*64 + vk];
                    oacc[dt] = __builtin_amdgcn_mfma_f32_16x16x32_bf16(pf,  vf2, oacc[dt], 0,0,0);
                    oacc[dt] = __builtin_amdgcn_mfma_f32_16x16x32_bf16(pfl, vf,  oacc[dt], 0,0,0);
                }
            }
        }
        __syncthreads();
    }
    int b = bh>>4, h = bh&15;
    #pragma unroll
    for (int j=0;j<4;++j){
        float inv = 1.f/lrow[j];
        int srowo = qt*64 + w*16 + hi*4 + j;
        size_t obase = ((size_t)b*2048 + srowo)*1024 + h*64;
        #pragma unroll
        for (int dt=0;dt<4;++dt){
            float v = oacc[dt][j]*inv;
            u16 hh = f2b(v);
            oh[obase + dt*16 + rr] = hh;
            if (SPLIT) ol[obase + dt*16 + rr] = f2b(v - b2f(hh));
        }
    }
}

// ---------------- gating + routing (verified r17) ----------------
__global__ __launch_bounds__(256) void gating_top2(
    const float* __restrict__ h, const float* __restrict__ Wg,
    int* __restrict__ e0, int* __restrict__ e1,
    float* __restrict__ w0, float* __restrict__ w1){
    int t = blockIdx.x*4 + (threadIdx.x>>6);
    int lane = threadIdx.x & 63;
    const float* xr = h + (size_t)t*1024;
    float s[8] = {0,0,0,0,0,0,0,0};
    #pragma unroll
    for (int i=0;i<16;++i){
        int d = lane*16 + i;
        float xv = xr[d];
        const float* wr = Wg + d*8;
        #pragma unroll
        for (int ee=0;ee<8;++ee) s[ee] += xv * wr[ee];
    }
    #pragma unroll
    for (int off=1;off<64;off<<=1){
        #pragma unroll
        for (int ee=0;ee<8;++ee) s[ee] += __shfl_xor(s[ee], off);
    }
    if (lane == 0){
        int b0 = 0; float v0 = s[0];
        #pragma unroll
        for (int ee=1;ee<8;++ee) if (s[ee] > v0){ v0 = s[ee]; b0 = ee; }
        int b1i = -1; float v1 = -3e38f;
        #pragma unroll
        for (int ee=0;ee<8;++ee) if (ee != b0 && s[ee] > v1){ v1 = s[ee]; b1i = ee; }
        float z = __expf(v1 - v0);
        float inv = 1.f/(1.f + z);
        e0[t] = b0; e1[t] = b1i; w0[t] = inv; w1[t] = z*inv;
    }
}

__global__ __launch_bounds__(512) void routing_kernel(
    const int* __restrict__ e0, const int* __restrict__ e1,
    int* __restrict__ tok, int* __restrict__ slotA, int* __restrict__ slotB,
    int* __restrict__ counts, int* __restrict__ offs){
    int w = threadIdx.x>>6, lane = threadIdx.x & 63;
    __shared__ int soff[8];
    unsigned long long below = (1ull << lane) - 1ull;
    int c = 0;
    for (int base=0; base<4096; base+=64){
        int t = base + lane;
        bool f = (e0[t]==w) | (e1[t]==w);
        c += __popcll(__ballot(f));
    }
    if (lane == 0) soff[w] = c;
    __syncthreads();
    if (threadIdx.x == 0){
        int r = 0;
        for (int i=0;i<8;++i){ int ci = soff[i]; counts[i] = ci; offs[i] = r; soff[i] = r; r += ci; }
    }
    __syncthreads();
    int run = soff[w];
    for (int base=0; base<4096; base+=64){
        int t = base + lane;
        bool f0 = (e0[t]==w), f1 = (e1[t]==w);
        bool f = f0 | f1;
        unsigned long long m = __ballot(f);
        int pos = __popcll(m & below);
        if (f){
            int sl = run + pos;
            tok[sl] = t;
            if (f0) slotA[t] = sl; else slotB[t] = sl;
        }
        run += __popcll(m);
    }
}

// ---------------- launcher ----------------
extern "C" void kernel_launch(void* const* d_in, const int* in_sizes, int n_in,
                              void* d_out, int out_size, void* d_ws, size_t ws_size,
                              hipStream_t stream){
    const float* x  = (const float*)d_in[0];
    const float* Wq = (const float*)d_in[1];
    const float* Wk = (const float*)d_in[2];
    const float* Wv = (const float*)d_in[3];
    const float* Wo = (const float*)d_in[4];
    const float* qs = (const float*)d_in[5];
    const float* ks = (const float*)d_in[6];
    const float* Wg = (const float*)d_in[7];
    const float* W1 = (const float*)d_in[8];
    const float* b1 = (const float*)d_in[9];
    const float* W2 = (const float*)d_in[10];
    const float* b2 = (const float*)d_in[11];

    char* base = (char*)d_ws;
    const size_t MB = 1024*1024;

    float* qkvf = (float*)base;                // 0-48  (attn phase)
    float* Mo   = (float*)base;                // MoE: 0-32
    u16*   afhi = (u16*)  (base + 48*MB);      // 48-56  attn out hi (bf16)
    u16*   aflo = (u16*)  (base + 56*MB);      // 56-64  attn out lo
    u16*   qhbh = (u16*)  (base + 64*MB);
    u16*   khbh = (u16*)  (base + 72*MB);
    u16*   vtbh = (u16*)  (base + 80*MB);
    u16*   qhbl = (u16*)  (base + 88*MB);
    u16*   khbl = (u16*)  (base + 96*MB);
    u16*   vtbl = (u16*)  (base + 104*MB);
    u16*   xhi  = (u16*)  (base + 112*MB);
    u16*   xlo  = (u16*)  (base + 120*MB);
    u16*   xb   = (u16*)  (base + 128*MB);
    u16*   wTh  = (u16*)  (base + 136*MB);
    u16*   wTl  = (u16*)  (base + 144*MB);
    u16*   w2Th = (u16*)  (base + 152*MB);
    u16*   w2Tl = (u16*)  (base + 160*MB);
    // grouped MoE regions
    u16*   W1Th = (u16*)  (base + 32*MB);      // 32-96
    u16*   W1Tl = (u16*)  (base + 136*MB);     // 136-200
    u16*   W2Thb= (u16*)  (base + 200*MB);     // 200-264
    u16*   W2Tlb= (u16*)  (base + 264*MB);     // 264-328
    u16*   HeH  = (u16*)  (base + 328*MB);     // 328-392
    u16*   HeL  = (u16*)  (base + 392*MB);     // 392-456
    u16*   He16g= (u16*)  (base + 200*MB);     // L1 W2T
    // routing data
    char*  rbase = base + (size_t)458*MB;
    int*   e0b  = (int*)  rbase;
    int*   e1b  = e0b + 4096;
    float* w0b  = (float*)(e1b + 4096);
    float* w1b  = w0b + 4096;
    int*   tok  = (int*)(w1b + 4096);
    int*   slA  = tok + 8192;
    int*   slB  = slA + 4096;
    int*   cnts = slB + 4096;
    int*   offs = cnts + 8;

    float* hf = (float*)d_out;
    const size_t HTOK = (size_t)4096*1024;

    const size_t WSTRIDE = (size_t)1024*1024;
    const size_t ESTRIDE = (size_t)1024*4096;

    // =================== LAYER 0 (split-bf16: fp32-grade h1) ===================
    {
        init_split<<<16384,256,0,stream>>>(x, hf, xhi, xlo, (int)HTOK);
        gating_top2<<<1024,256,0,stream>>>(hf, Wg, e0b,e1b,w0b,w1b);
        routing_kernel<<<1,512,0,stream>>>(e0b,e1b, tok,slA,slB, cnts,offs);

        transpose_split<<<dim3(32,32),dim3(32,8),0,stream>>>(Wq, wTh,           wTl,           1024,1024);
        transpose_split<<<dim3(32,32),dim3(32,8),0,stream>>>(Wk, wTh + 1048576, wTl + 1048576, 1024,1024);
        transpose_split<<<dim3(32,32),dim3(32,8),0,stream>>>(Wv, wTh + 2097152, wTl + 2097152, 1024,1024);
        mgemm_s<0><<<dim3(24,32),256,0,stream>>>(xhi, xlo, wTh, wTl, qkvf, 4096,3072,1024,3072);

        qknorm_out<<<1024,256,0,stream>>>(qkvf, qs, ks, qhbh, qhbl, khbh, khbl, 1);
        transpose_v<<<dim3(64,2,32),dim3(32,8),0,stream>>>(qkvf, vtbh, vtbl, 1);
        attn_flash<1><<<dim3(32,32),256,0,stream>>>(qhbh, qhbl, khbh, khbl, vtbh, vtbl, afhi, aflo);

        transpose_split<<<dim3(32,32),dim3(32,8),0,stream>>>(Wo, w2Th, w2Tl, 1024,1024);
        mgemm_s<1><<<dim3(8,32),256,0,stream>>>(afhi, aflo, w2Th, w2Tl, hf, 4096,1024,1024,1024);

        transpose_split_z<<<dim3(128,32,8),dim3(32,8),0,stream>>>(W1, W1Th, W1Tl, 1024,4096, ESTRIDE, (size_t)4096*1024);
        transpose_split_z<<<dim3(32,128,8),dim3(32,8),0,stream>>>(W2, W2Thb, W2Tlb, 4096,1024, ESTRIDE, (size_t)1024*4096);
        mgemm_gs<true ><<<dim3(32,32,8),256,0,stream>>>(xhi, xlo, W1Th, W1Tl, nullptr, HeH, HeL, b1, tok,cnts,offs, 4096,1024);
        mgemm_gs<false><<<dim3(8,32,8),256,0,stream>>>(HeH, HeL, W2Thb, W2Tlb, Mo, nullptr,nullptr, nullptr, tok,cnts,offs, 1024,4096);

        combine_kernel<<<4096,256,0,stream>>>(hf, Mo, slA,slB, e0b,e1b, w0b,w1b, b2, xb);
    }

    // =================== LAYER 1 (plain bf16) ===================
    {
        gating_top2<<<1024,256,0,stream>>>(hf, Wg + (size_t)1024*8, e0b,e1b,w0b,w1b);
        routing_kernel<<<1,512,0,stream>>>(e0b,e1b, tok,slA,slB, cnts,offs);

        transpose_cvt<<<dim3(32,32),dim3(32,8),0,stream>>>(Wq + WSTRIDE, wTh,           1024,1024);
        transpose_cvt<<<dim3(32,32),dim3(32,8),0,stream>>>(Wk + WSTRIDE, wTh + 1048576, 1024,1024);
        transpose_cvt<<<dim3(32,32),dim3(32,8),0,stream>>>(Wv + WSTRIDE, wTh + 2097152, 1024,1024);
        mgemm<0><<<dim3(24,32),256,0,stream>>>(xb, wTh, qkvf, nullptr, nullptr,nullptr, 4096,3072,1024,3072);

        qknorm_out<<<1024,256,0,stream>>>(qkvf, qs + 64, ks + 64, qhbh, nullptr, khbh, nullptr, 0);
        transpose_v<<<dim3(64,2,32),dim3(32,8),0,stream>>>(qkvf, vtbh, nullptr, 0);
        attn_flash<0><<<dim3(32,32),256,0,stream>>>(qhbh, nullptr, khbh, nullptr, vtbh, nullptr, afhi, nullptr);

        transpose_cvt<<<dim3(32,32),dim3(32,8),0,stream>>>(Wo + WSTRIDE, w2Th, 1024,1024);
        mgemm<1><<<dim3(8,32),256,0,stream>>>(afhi, w2Th, hf, nullptr, nullptr,nullptr, 4096,1024,1024,1024);

        transpose_cvt_z<<<dim3(128,32,8),dim3(32,8),0,stream>>>(W1 + (size_t)8*ESTRIDE, W1Th, 1024,4096, ESTRIDE, (size_t)4096*1024);
        transpose_cvt_z<<<dim3(32,128,8),dim3(32,8),0,stream>>>(W2 + (size_t)8*ESTRIDE, He16g, 4096,1024, ESTRIDE, (size_t)1024*4096);
        mgemm_gp<true ><<<dim3(32,32,8),256,0,stream>>>(xb, W1Th, nullptr, (u16*)HeH, b1 + (size_t)8*4096, tok,cnts,offs, 4096,1024);
        mgemm_gp<false><<<dim3(8,32,8),256,0,stream>>>((u16*)HeH, He16g, Mo, nullptr, nullptr, tok,cnts,offs, 1024,4096);

        combine_kernel<<<4096,256,0,stream>>>(hf, Mo, slA,slB, e0b,e1b, w0b,w1b, b2 + (size_t)8*1024, nullptr);
    }
}